// Round 15
// baseline (538.211 us; speedup 1.0000x reference)
//
#include <hip/hip_runtime.h>
#include <math.h>

// Problem dims
#define NB 256
#define DM 126       // D_MODEL
#define DE 128       // D_EMB
#define NH 6
#define DHd 21
#define DFF 2048
#define CIN 75
#define L0 128
#define NTOP 25

#ifndef IDX_MODE
#define IDX_MODE 0
#endif

typedef const float* fp;
typedef unsigned short u16;
typedef short s8v __attribute__((ext_vector_type(8)));
typedef float f4v __attribute__((ext_vector_type(4)));

__device__ __forceinline__ u16 f2bf(float x){
  unsigned u = __float_as_uint(x);
  unsigned r = (u + 0x7FFFu + ((u >> 16) & 1u)) >> 16;
  return (u16)r;
}
__device__ __forceinline__ float bf2f(u16 v){
  unsigned uu = ((unsigned)v) << 16;
  return __uint_as_float(uu);
}

__device__ __forceinline__ void gld_lds16(const u16* g, u16* l){
  __builtin_amdgcn_global_load_lds((const __attribute__((address_space(1))) unsigned int*)(const void*)g,
                                   (__attribute__((address_space(3))) unsigned int*)(void*)l,
                                   16, 0, 0);
}

// pack 2 f32 -> 2 bf16 (RNE) in one VALU op
__device__ __forceinline__ unsigned cvt_pk_bf16(float lo, float hi){
  unsigned r;
  asm("v_cvt_pk_bf16_f32 %0, %1, %2" : "=v"(r) : "v"(lo), "v"(hi));
  return r;
}

__device__ __forceinline__ void tf2(unsigned k0, unsigned k1, unsigned x0, unsigned x1,
                                    unsigned &o0, unsigned &o1){
  unsigned ks2 = k0 ^ k1 ^ 0x1BD11BDAu;
  x0 += k0; x1 += k1;
  #define RR(r) { x0 += x1; x1 = (x1 << (r)) | (x1 >> (32 - (r))); x1 ^= x0; }
  RR(13) RR(15) RR(26) RR(6)
  x0 += k1;  x1 += ks2 + 1u;
  RR(17) RR(29) RR(16) RR(24)
  x0 += ks2; x1 += k0 + 2u;
  RR(13) RR(15) RR(26) RR(6)
  x0 += k0;  x1 += k1 + 3u;
  RR(17) RR(29) RR(16) RR(24)
  x0 += k1;  x1 += ks2 + 4u;
  RR(13) RR(15) RR(26) RR(6)
  x0 += ks2; x1 += k0 + 5u;
  #undef RR
  o0 = x0; o1 = x1;
}

// ---------------- fallback: zero output (ws too small diagnostic) ----------------
__global__ __launch_bounds__(256) void k_zero(float* out, int n){
  int i = blockIdx.x*256 + threadIdx.x;
  if (i < n) out[i] = 0.f;
}

// ============================================================================
// MERGED prep: idx (block 0) + wprep (blocks 1..835) + wtrans (836..1091).
// ============================================================================
__global__ __launch_bounds__(256) void k_prep(int* idx0, int* idx1,
                                              fp token_w, fp clw,
                                              fp qw, fp qb, fp kw, fp kb, fp vw, fp vb, fp ow,
                                              u16* wemb, u16* wdist, u16* wqkv, u16* wo,
                                              float* qbias,
                                              fp f1w, fp f2w, u16* w1t, u16* w2t){
  __shared__ u16 sT[64*65];
  const int blk = blockIdx.x;
  const int tid = threadIdx.x;
  if (blk == 0){
    unsigned a0,a1,c0,c1;
    tf2(0u,42u, 0u,0u, a0,a1);
    tf2(0u,42u, 0u,1u, c0,c1);
    for (int f = tid; f < 3200; f += 256){
      unsigned y0,y1;
#if IDX_MODE==0
      tf2(a0,a1, 0u, (unsigned)(3200+f), y0,y1); idx0[f] = (int)(y1 & 127u);
#elif IDX_MODE==1
      tf2(a0,a1, 0u, (unsigned)(3200+f), y0,y1); idx0[f] = (int)(y0 & 127u);
#elif IDX_MODE==2
      tf2(a0,a1, (unsigned)f, (unsigned)(3200+f), y0,y1); idx0[f] = (int)(y1 & 127u);
#else
      tf2(a0,a1, (unsigned)f, (unsigned)(3200+f), y0,y1); idx0[f] = (int)(y0 & 127u);
#endif
    }
    for (int f = tid; f < 1600; f += 256){
      unsigned y0,y1;
#if IDX_MODE==0
      tf2(c0,c1, 0u, (unsigned)(1600+f), y0,y1); idx1[f] = (int)(y1 & 63u);
#elif IDX_MODE==1
      tf2(c0,c1, 0u, (unsigned)(1600+f), y0,y1); idx1[f] = (int)(y0 & 63u);
#elif IDX_MODE==2
      tf2(c0,c1, (unsigned)f, (unsigned)(1600+f), y0,y1); idx1[f] = (int)(y1 & 63u);
#else
      tf2(c0,c1, (unsigned)f, (unsigned)(1600+f), y0,y1); idx1[f] = (int)(y0 & 63u);
#endif
    }
    return;
  }
  if (blk <= 835){
    int i = (blk - 1)*256 + tid;
    if (i < 32768){
      int n = i >> 8, k = i & 255;
      float v = 0.f;
      if (k < 225){ int q = k/75, c = k - q*75; v = token_w[(size_t)n*225 + c*3 + q]; }
      wemb[i] = f2bf(v);
      return;
    }
    i -= 32768;
    if (i < 49152){
      int n = i / 384, k = i - n*384;
      float v = 0.f;
      if (n < DM && k < 378){ int q = k/126, ci = k - q*126; v = clw[((size_t)n*DM + ci)*3 + q]; }
      wdist[i] = f2bf(v);
      return;
    }
    i -= 49152;
    if (i < 2*49152){
      int layer = i / 49152, jj = i - layer*49152;
      int n = jj >> 7, k = jj & 127;
      int sec = n >> 7, nn = n & 127;
      const float* w = (sec == 0) ? qw : ((sec == 1) ? kw : vw);
      float v = (nn < DM && k < DM) ? w[((size_t)layer*DM + k)*DM + nn] : 0.f;
      wqkv[(size_t)layer*49152 + jj] = f2bf(v);
      return;
    }
    i -= 2*49152;
    if (i < 2*16384){
      int layer = i / 16384, jj = i - layer*16384;
      int n = jj >> 7, k = jj & 127;
      float v = (n < DM && k < DM) ? ow[(size_t)layer*DM*DM + k*DM + n] : 0.f;
      wo[(size_t)layer*16384 + jj] = f2bf(v);
      return;
    }
    i -= 2*16384;
    if (i < 768){
      int layer = i / 384, n = i - layer*384;
      int sec = n >> 7, nn = n & 127;
      const float* bp = (sec == 0) ? qb : ((sec == 1) ? kb : vb);
      qbias[(size_t)layer*384 + n] = (nn < DM) ? bp[layer*DM + nn] : 0.f;
    }
    return;
  }
  // ---- wtrans: coalesced LDS-tiled transposes of f1w/f2w ----
  {
    const int t = blk - 836;
    const int lane = tid & 63, rg = tid >> 6;
    if (t < 128){
      int layer = t >> 6, rem = t & 63;
      int kt = rem >> 5, nt = rem & 31;
      #pragma unroll
      for (int rr = 0; rr < 16; rr++){
        int row = rg + rr*4;
        int k = kt*64 + row;
        float v = (k < DM) ? f1w[((size_t)layer*DM + k)*DFF + nt*64 + lane] : 0.f;
        sT[row*65 + lane] = f2bf(v);
      }
      __syncthreads();
      #pragma unroll
      for (int rr = 0; rr < 16; rr++){
        int nrow = rg + rr*4;
        int n_glob = nt*64 + nrow;
        w1t[(size_t)layer*262144 + (size_t)n_glob*128 + kt*64 + lane] = sT[lane*65 + nrow];
      }
    } else {
      int t2 = t - 128;
      int layer = t2 >> 6, rem = t2 & 63;
      int nt = rem >> 5, ft = rem & 31;
      #pragma unroll
      for (int rr = 0; rr < 16; rr++){
        int row = rg + rr*4;
        int f = ft*64 + row;
        int n = nt*64 + lane;
        float v = (n < DM) ? f2w[((size_t)layer*DFF + f)*DM + n] : 0.f;
        sT[row*65 + lane] = f2bf(v);
      }
      __syncthreads();
      #pragma unroll
      for (int rr = 0; rr < 16; rr++){
        int nrow = rg + rr*4;
        int n_glob = nt*64 + nrow;
        w2t[(size_t)layer*262144 + (size_t)n_glob*2048 + ft*64 + lane] = sT[lane*65 + nrow];
      }
    }
  }
}

// ============================================================================
// FUSED front: token-embed(conv K=225 + pos + time) -> attn scalars -> ODConv.
// ============================================================================
__global__ __launch_bounds__(256) void k_front(fp x_enc, fp x_mark, const u16* wemb,
                                               fp time_w, fp time_b,
                                               fp fcw, fp bng, fp bnb,
                                               fp chw, fp chb, fp filw, fp filb,
                                               fp spw, fp spb, fp kerw, fp kerb,
                                               fp odw, float* xout){
  __shared__ __align__(16) u16 smem[71232];
  u16*   sXT = smem;
  u16*   sW  = smem + 17680;
  u16*   sA  = smem + 17680;
  float* sE  = reinterpret_cast<float*>(smem + 17680);
  float* red = reinterpret_cast<float*>(smem + 69904);
  float* gap = reinterpret_cast<float*>(smem + 70416);
  float* aAct= reinterpret_cast<float*>(smem + 70672);
  float* sch = reinterpret_cast<float*>(smem + 70704);
  float* sfil= reinterpret_cast<float*>(smem + 70960);
  float* ssp = reinterpret_cast<float*>(smem + 71216);
  float* sker= reinterpret_cast<float*>(smem + 71224);
  const int tid = threadIdx.x;
  const int wave = tid >> 6, lane = tid & 63, quad = lane >> 4, l15 = lane & 15;
  const int b = blockIdx.x;
  const f4v z4 = {0.f,0.f,0.f,0.f};
  const int mBase = wave * 32;

  // ---- phase 1: conv input staging ----
  {
    const float4* xb = reinterpret_cast<const float4*>(x_enc + (size_t)b*L0*CIN);
    for (int p4 = tid; p4 < (L0*CIN)/4; p4 += 256){
      float4 v4 = xb[p4];
      float vv[4] = {v4.x, v4.y, v4.z, v4.w};
      int e0 = p4*4;
      #pragma unroll
      for (int j = 0; j < 4; j++){
        int e = e0 + j;
        int sr = e / CIN, c = e - sr*CIN;
        u16 bv = f2bf(vv[j]);
        sA[((sr + 1) & 127)*264 + c] = bv;
        sA[sr*264 + 75 + c] = bv;
        sA[((sr + 127) & 127)*264 + 150 + c] = bv;
      }
    }
    for (int p = tid; p < 128*31; p += 256){
      int row = p / 31, c2 = p - row*31;
      sA[row*264 + 225 + c2] = 0;
    }
  }
  __syncthreads();
  // ---- phase 1b: MFMA + epilogue -> sE ----
  {
    f4v acc[2][8];
    #pragma unroll
    for (int m = 0; m < 2; m++)
      #pragma unroll
      for (int t = 0; t < 8; t++) acc[m][t] = z4;
    for (int ks = 0; ks < 8; ks++){
      s8v a0 = *reinterpret_cast<const s8v*>(sA + (mBase + l15)*264 + ks*32 + quad*8);
      s8v a1 = *reinterpret_cast<const s8v*>(sA + (mBase + 16 + l15)*264 + ks*32 + quad*8);
      const u16* wb = wemb + (size_t)l15*256 + ks*32 + quad*8;
      #pragma unroll
      for (int t = 0; t < 8; t++){
        s8v bfr = *reinterpret_cast<const s8v*>(wb + (size_t)t*16*256);
        acc[0][t] = __builtin_amdgcn_mfma_f32_16x16x32_bf16(a0, bfr, acc[0][t], 0, 0, 0);
        acc[1][t] = __builtin_amdgcn_mfma_f32_16x16x32_bf16(a1, bfr, acc[1][t], 0, 0, 0);
      }
    }
    float divc[8], tw0c[8], tw1c[8], tw2c[8], tbc[8];
    #pragma unroll
    for (int t = 0; t < 8; t++){
      int col = t*16 + l15;
      int i2 = col >> 1;
      divc[t] = __expf((float)(2*i2) * (-9.210340371976184f / 128.f));
      tw0c[t] = time_w[col]; tw1c[t] = time_w[128 + col]; tw2c[t] = time_w[256 + col];
      tbc[t] = time_b[col];
    }
    #pragma unroll
    for (int m = 0; m < 2; m++){
      #pragma unroll
      for (int r = 0; r < 4; r++){
        int row = mBase + m*16 + quad*4 + r;
        const float* mk = x_mark + ((size_t)b*L0 + row)*3;
        float m0v = mk[0], m1v = mk[1], m2v = mk[2];
        #pragma unroll
        for (int t = 0; t < 8; t++){
          int col = t*16 + l15;
          float ang = (float)row * divc[t];
          float pe = (col & 1) ? __cosf(ang) : __sinf(ang);
          float tm = m0v*tw0c[t] + m1v*tw1c[t] + m2v*tw2c[t] + tbc[t];
          sE[row*132 + col] = acc[m][t][r] + pe + tm;
        }
      }
    }
  }
  __syncthreads();
  // ---- phase 2: attention scalars ----
  {
    int col = tid & 127, half = tid >> 7;
    float s = 0.f;
    for (int r = 0; r < 64; r++) s += sE[(half*64 + r)*132 + col];
    red[tid] = s;
  }
  __syncthreads();
  if (tid < 128) gap[tid] = (red[tid] + red[tid + 128]) * (1.f/128.f);
  __syncthreads();
  if (tid < 16){
    float acc = 0.f;
    for (int e = 0; e < DE; e++) acc += gap[e]*fcw[e*16 + tid];
    acc = acc * (bng[tid] / sqrtf(1.f + 1e-5f)) + bnb[tid];
    aAct[tid] = fmaxf(acc, 0.f);
  }
  __syncthreads();
  if (tid < 128){
    float accc = 0.f, accf = 0.f;
    for (int c = 0; c < 16; c++){ accc += aAct[c]*chw[c*DE + tid]; accf += aAct[c]*filw[c*DE + tid]; }
    sch[tid]  = 1.f/(1.f + __expf(-(accc + chb[tid])));
    sfil[tid] = 1.f/(1.f + __expf(-(accf + filb[tid])));
  } else if (tid < 131){
    int t = tid - 128;
    float acc = 0.f;
    for (int c = 0; c < 16; c++) acc += aAct[c]*spw[c*3 + t];
    ssp[t] = 1.f/(1.f + __expf(-(acc + spb[t])));
  } else if (tid == 132){
    float v[4]; float mx = -1e30f;
    for (int n = 0; n < 4; n++){
      float acc = 0.f;
      for (int c = 0; c < 16; c++) acc += aAct[c]*kerw[c*4 + n];
      v[n] = acc + kerb[n]; mx = fmaxf(mx, v[n]);
    }
    float ss = 0.f;
    for (int n = 0; n < 4; n++){ v[n] = __expf(v[n]-mx); ss += v[n]; }
    for (int n = 0; n < 4; n++) sker[n] = v[n]/ss;
  }
  __syncthreads();
  // ---- phase 3a: sXT = emb * ch ----
  for (int p = tid; p < 130*128; p += 256){
    int l = p >> 7, i = p & 127;
    float v = (l < 128) ? sE[l*132 + i]*sch[i] : 0.f;
    sXT[l*136 + i] = f2bf(v);
  }
  __syncthreads();
  // ---- phase 3b: aggregate weights -> sW ----
  {
    float kr0 = sker[0], kr1 = sker[1], kr2 = sker[2], kr3 = sker[3];
    float spq[3]; spq[0] = ssp[0]; spq[1] = ssp[1]; spq[2] = ssp[2];
    const float4* od4 = (const float4*)odw;
    for (int p4 = tid; p4 < 128*384/4; p4 += 256){
      float4 w0 = od4[p4];
      float4 w1 = od4[12288 + p4];
      float4 w2 = od4[24576 + p4];
      float4 w3 = od4[36864 + p4];
      float vv[4] = { kr0*w0.x + kr1*w1.x + kr2*w2.x + kr3*w3.x,
                      kr0*w0.y + kr1*w1.y + kr2*w2.y + kr3*w3.y,
                      kr0*w0.z + kr1*w1.z + kr2*w2.z + kr3*w3.z,
                      kr0*w0.w + kr1*w1.w + kr2*w2.w + kr3*w3.w };
      int e0 = p4*4;
      #pragma unroll
      for (int j = 0; j < 4; j++){
        int e = e0 + j;
        int o = e / 384, rem = e - o*384;
        int i = rem / 3, q = rem - i*3;
        sW[(q*128 + o)*136 + i] = f2bf(vv[j] * spq[q]);
      }
    }
  }
  __syncthreads();
  // ---- phase 3c: ODConv MFMA + gated store ----
  {
    f4v acc[2][8];
    #pragma unroll
    for (int m = 0; m < 2; m++)
      #pragma unroll
      for (int t = 0; t < 8; t++) acc[m][t] = z4;
    for (int q = 0; q < 3; q++){
      const u16* wq = sW + q*128*136;
      #pragma unroll
      for (int ks = 0; ks < 4; ks++){
        s8v a0 = *reinterpret_cast<const s8v*>(wq + (mBase + l15)*136 + ks*32 + quad*8);
        s8v a1 = *reinterpret_cast<const s8v*>(wq + (mBase + 16 + l15)*136 + ks*32 + quad*8);
        #pragma unroll
        for (int t = 0; t < 8; t++){
          s8v bfr = *reinterpret_cast<const s8v*>(sXT + (t*16 + l15 + q)*136 + ks*32 + quad*8);
          acc[0][t] = __builtin_amdgcn_mfma_f32_16x16x32_bf16(a0, bfr, acc[0][t], 0, 0, 0);
          acc[1][t] = __builtin_amdgcn_mfma_f32_16x16x32_bf16(a1, bfr, acc[1][t], 0, 0, 0);
        }
      }
    }
    #pragma unroll
    for (int t = 0; t < 8; t++){
      int tt = t*16 + l15;
      if (tt < DM){
        #pragma unroll
        for (int m = 0; m < 2; m++){
          #pragma unroll
          for (int r = 0; r < 4; r++){
            int o = mBase + m*16 + quad*4 + r;
            xout[((size_t)b*DE + o)*DM + tt] = sfil[o] * acc[m][t][r];
          }
        }
      }
    }
  }
}

// ---------------- fused QKV GEMM (L0 only): Q,K -> qkv[M][256]; V -> vt(bf16) --
__global__ __launch_bounds__(256) void k_qkv_mfma(const float* xin, const u16* wqkv,
                                                  const float* qkvb, float* qkv,
                                                  u16* vt, int L, int lshift, int lmask){
  __shared__ __align__(16) u16 sX[64*136];
  const int tid = threadIdx.x;
  const int wave = tid >> 6, lane = tid & 63, quad = lane >> 4, l15 = lane & 15;
  const size_t rows0 = (size_t)blockIdx.x * 64;
  for (int p = tid; p < 64*128; p += 256){
    int r = p >> 7, c = p & 127;
    float v = (c < DM) ? xin[(rows0 + r)*DM + c] : 0.f;
    sX[r*136 + c] = f2bf(v);
  }
  __syncthreads();
  const f4v z4 = {0.f,0.f,0.f,0.f};
  f4v acc[24];
  #pragma unroll
  for (int t = 0; t < 24; t++) acc[t] = z4;
  const int m0 = wave * 16;
  #pragma unroll
  for (int ks = 0; ks < 4; ks++){
    s8v a = *reinterpret_cast<const s8v*>(sX + (m0 + l15)*136 + ks*32 + quad*8);
    const u16* wb = wqkv + (size_t)l15*128 + ks*32 + quad*8;
    #pragma unroll
    for (int t = 0; t < 24; t++){
      s8v b = *reinterpret_cast<const s8v*>(wb + (size_t)t*16*128);
      acc[t] = __builtin_amdgcn_mfma_f32_16x16x32_bf16(a, b, acc[t], 0, 0, 0);
    }
  }
  #pragma unroll
  for (int t = 0; t < 24; t++){
    int col = t*16 + l15;
    float bv = qkvb[col];
    if (col < 256){
      #pragma unroll
      for (int r = 0; r < 4; r++){
        int row = m0 + quad*4 + r;
        qkv[(rows0 + row)*256 + col] = acc[t][r] + bv;
      }
    } else {
      int c = col - 256;
      if (c < DM){
        int h = c / DHd, d = c - h*DHd;
        #pragma unroll
        for (int r = 0; r < 4; r++){
          int gr = (int)rows0 + m0 + quad*4 + r;
          int b = gr >> lshift, l = gr & lmask;
          vt[((size_t)(b*NH + h)*DHd + d)*L + l] = f2bf(acc[t][r] + bv);
        }
      }
    }
  }
}

// ============================================================================
// FUSED attention v2: one bh per 128-thread block, grid B*H.
// VT/upd/vmean bf16 (bit-identical: f2bf moved producer-side).
// ============================================================================
__global__ __launch_bounds__(128) void k_attn(const float* qkv, const u16* vt,
                                              const int* idx, int L,
                                              int* posmap, u16* vmean, u16* upd){
  __shared__ __align__(16) float sK[2816];
  __shared__ int sTop[32];
  const int tid = threadIdx.x;
  const int wave = tid >> 6, lane = tid & 63, quad = lane >> 4, l15 = lane & 15;
  const int bh = blockIdx.x;
  const int b = bh / NH, h = bh - b*NH;
  float* sM = sK + 2688;
  u16* sPb = reinterpret_cast<u16*>(sK);
  const float* qbase = qkv + (size_t)(b*L)*256 + h*DHd;
  const u16* vb = vt + (size_t)bh*DHd*L;
  const f4v z4 = {0.f,0.f,0.f,0.f};
  const int ntn = L >> 4;
  const int d0 = quad*8;
  const int mt = wave;

  for (int p = tid; p < L*DHd; p += 128){
    int l = p / DHd, d = p - l*DHd;
    sK[p] = qbase[(size_t)l*256 + 128 + d];
  }
  posmap[bh*L0 + tid] = -1;
  __syncthreads();
  if (tid < L){
    const int l = tid;
    const float* qg = qbase + (size_t)l*256;
    float qr[DHd];
    #pragma unroll
    for (int d = 0; d < DHd; d++) qr[d] = qg[d];
    float mx = -1e30f, sm = 0.f;
    #pragma unroll
    for (int u = 0; u < NTOP; u++){
      int kk = idx[l*NTOP + u];
      const float* kp = sK + kk*DHd;
      float acc = 0.f;
      #pragma unroll
      for (int d = 0; d < DHd; d++) acc += qr[d]*kp[d];
      mx = fmaxf(mx, acc); sm += acc;
    }
    sM[l] = mx - sm/(float)L;
  }
  __syncthreads();
  if (wave == 0){
    for (int it = 0; it < NTOP; it++){
      float bv = sM[lane]; int bi = lane;
      if (L == 128){
        float v1 = sM[lane + 64];
        if (v1 > bv){ bv = v1; bi = lane + 64; }
      }
      #pragma unroll
      for (int off = 32; off > 0; off >>= 1){
        float ov = __shfl_xor(bv, off);
        int   oi = __shfl_xor(bi, off);
        if (ov > bv || (ov == bv && oi < bi)){ bv = ov; bi = oi; }
      }
      if (lane == 0){
        sM[bi] = -1e30f;
        posmap[bh*L0 + bi] = it;
        sTop[it] = bi;
      }
    }
  }
  __syncthreads();

  s8v aq;
  {
    int uu = mt*16 + l15; if (uu >= NTOP) uu = 0;
    int r = sTop[uu];
    const float* qp = qbase + (size_t)r*256 + d0;
    #pragma unroll
    for (int j = 0; j < 8; j++) aq[j] = (short)f2bf(qp[j]);
  }
  f4v sc[8];
  for (int nt = 0; nt < ntn; nt++){
    const float* kp = sK + (size_t)(nt*16 + l15)*DHd + d0;
    s8v bb;
    #pragma unroll
    for (int j = 0; j < 8; j++) bb[j] = (d0 + j < DHd) ? (short)f2bf(kp[j]) : (short)0;
    sc[nt] = __builtin_amdgcn_mfma_f32_16x16x32_bf16(aq, bb, z4, 0, 0, 0);
  }
  __syncthreads();
  const float inv21 = 0.21821789023599236f;
  #pragma unroll
  for (int r4 = 0; r4 < 4; r4++){
    float mx = -1e30f;
    for (int nt = 0; nt < ntn; nt++) mx = fmaxf(mx, sc[nt][r4]*inv21);
    #pragma unroll
    for (int off = 1; off < 16; off <<= 1) mx = fmaxf(mx, __shfl_xor(mx, off));
    float e[8]; float ss = 0.f;
    for (int nt = 0; nt < ntn; nt++){ e[nt] = __expf(sc[nt][r4]*inv21 - mx); ss += e[nt]; }
    #pragma unroll
    for (int off = 1; off < 16; off <<= 1) ss += __shfl_xor(ss, off);
    float dn = 1.f / ss;
    int u = mt*16 + quad*4 + r4;
    for (int nt = 0; nt < ntn; nt++)
      sPb[u*136 + nt*16 + l15] = f2bf(e[nt]*dn);
  }
  if (wave == 1){
    u16 invL = f2bf(1.f/(float)L);
    for (int c = lane; c < L; c += 64) sPb[25*136 + c] = invL;
  }
  f4v pv[2];
  pv[0] = z4; pv[1] = z4;
  int kSteps = L >> 5;
  for (int ks = 0; ks < kSteps; ks++){
    #pragma unroll
    for (int nt = 0; nt < 2; nt++){
      int d = nt*16 + l15;
      s8v bb;
      if (d < DHd){
        const u16* vp = vb + (size_t)d*L + ks*32 + d0;   // bf16, 16B consecutive
        #pragma unroll
        for (int j = 0; j < 8; j++) bb[j] = (short)vp[j];
      } else {
        #pragma unroll
        for (int j = 0; j < 8; j++) bb[j] = (short)0;
      }
      s8v a = *reinterpret_cast<const s8v*>(sPb + (mt*16 + l15)*136 + ks*32 + d0);
      pv[nt] = __builtin_amdgcn_mfma_f32_16x16x32_bf16(a, bb, pv[nt], 0, 0, 0);
    }
  }
  #pragma unroll
  for (int nt = 0; nt < 2; nt++){
    #pragma unroll
    for (int r4 = 0; r4 < 4; r4++){
      int u = mt*16 + quad*4 + r4;
      int d = nt*16 + l15;
      if (d < DHd){
        if (u < NTOP)       upd[((size_t)bh*NTOP + u)*DHd + d] = f2bf(pv[nt][r4]);
        else if (u == NTOP) vmean[bh*DHd + d] = f2bf(pv[nt][r4]);
      }
    }
  }
}

// fast GELU in log2 domain
__device__ __forceinline__ float gelu_fast(float x){
  float x2 = x*x;
  float u = x * __builtin_fmaf(0.10295128f, x2, 2.30212056f);
  u = fminf(u, 126.f);
#if __has_builtin(__builtin_amdgcn_exp2f)
  float t = __builtin_amdgcn_exp2f(u);
#else
  float t = __expf(u * 0.69314718056f);
#endif
  return x * t * __builtin_amdgcn_rcpf(t + 1.f);
}

// ============================================================================
// FFN v12 = v11 + parallel LN stats (8 threads/row, was 2x63-serial),
// parallel fc tail (8 threads/col), posmap staged to LDS.
// NOTE: LN-stat / fc summation ORDER changes (63+63 -> 8x16 groups) — value
// drift ~1e-6, far below the bf16-quantum absmax (0.0234375).
// ============================================================================

__device__ __forceinline__ void stage_w1_p(const u16* w1t, int j, u16* buf, int p){
  int n = p >> 4, c = p & 15;
  int cg = c ^ (n & 7);
  gld_lds16(w1t + (((size_t)(j*64 + n)) << 7) + cg*8,
            buf + (size_t)((p >> 6) << 6)*8);
}
__device__ __forceinline__ void stage_w2_p(const u16* w2t, int j, u16* buf, int p){
  int n = p >> 3, c = p & 7;
  int cg = c ^ (n & 7);
  gld_lds16(w2t + (size_t)n*2048 + j*64 + cg*8,
            buf + (size_t)((p >> 6) << 6)*8);
}

// Y-tile address: [MR rows][64 K] u16, granule(8 u16 = 16B) XOR'd by row&7
__device__ __forceinline__ int yaddr(int row, int col){
  return row*64 + (((col >> 3) ^ (row & 7)) << 3) + (col & 7);
}

__device__ __forceinline__ void lgkm_barrier(){
  asm volatile("s_waitcnt lgkmcnt(0)" ::: "memory");
  __builtin_amdgcn_sched_barrier(0);
  __builtin_amdgcn_s_barrier();
  __builtin_amdgcn_sched_barrier(0);
}

// 8-way parallel LN stats on sO[rows][129]: mean/rstd per row.
template<int ROWS>
__device__ __forceinline__ void ln_stats(const float* sO, float* prs,
                                         float* smean, float* srstd, int tid){
  if (tid < 8*ROWS){
    int row = tid >> 3, gcol = (tid & 7)*16;
    float s = 0.f;
    #pragma unroll
    for (int c = 0; c < 16; c++){
      int cc = gcol + c;
      if (cc < DM) s += sO[row*129 + cc];
    }
    prs[tid] = s;
  }
  __syncthreads();
  if (tid < ROWS){
    float s = 0.f;
    #pragma unroll
    for (int k = 0; k < 8; k++) s += prs[tid*8 + k];
    smean[tid] = s / (float)DM;
  }
  __syncthreads();
  if (tid < 8*ROWS){
    int row = tid >> 3, gcol = (tid & 7)*16;
    float mn = smean[row];
    float s = 0.f;
    #pragma unroll
    for (int c = 0; c < 16; c++){
      int cc = gcol + c;
      if (cc < DM){ float d = sO[row*129 + cc] - mn; s += d*d; }
    }
    prs[tid] = s;
  }
  __syncthreads();
  if (tid < ROWS){
    float s = 0.f;
    #pragma unroll
    for (int k = 0; k < 8; k++) s += prs[tid*8 + k];
    srstd[tid] = rsqrtf(s / (float)DM + 1e-5f);
  }
  __syncthreads();
}

template<int ROWS>
__global__ __launch_bounds__(1024) void k_ffn(const u16* w1t, const u16* w2t,
                                              fp b1, fp b2w, fp g, fp bb, int layer,
                                              const u16* wdist, fp e1, fp e2, fp e3, fp e4,
                                              const float* xres, const u16* vmeanp,
                                              const int* posmapp, const u16* updp,
                                              const u16* wo, fp obp, fp l1g, fp l1b,
                                              const u16* wqkv1, fp qb1, float* qkvout, u16* vtout,
                                              float* out2){
  constexpr int NT   = 1024;
  constexpr int MR   = ROWS/4;        // rows per mg-group (32 or 16)
  constexpr int MT2  = MR/16;         // m-tiles per wave in loop (2 or 1)
  constexpr int RSH  = (ROWS == 128) ? 7 : 6;
  constexpr int SYG  = ROWS*64;       // 4 mg Y tiles (u16)
  constexpr int XMOFF = SYG + 4*8192; // u16 offset of in-LDS xmid
  constexpr int TAILU = (ROWS == 128) ? 128*392 : 0;
  constexpr int XMEND = XMOFF + ROWS*130*2;
  constexpr int SMEMU = (XMEND > TAILU) ? XMEND : TAILU;
  __shared__ __align__(16) u16 smem[SMEMU];
  __shared__ float prs[1024];
  __shared__ float smean[ROWS], srstd[ROWS];
  __shared__ int sPos[NH*128];
  u16* wA0 = smem + SYG;
  u16* wA1 = wA0 + 8192;
  u16* wB0 = wA1 + 8192;
  u16* wB1 = wB0 + 8192;
  const int tid  = threadIdx.x;
  const int wave = tid >> 6, lane = tid & 63, quad = lane >> 4, l15 = lane & 15;
  const int mg = wave >> 2, ng = wave & 3;
  const int rowb = mg * MR;
  u16* sYg = smem + mg*(MR*64);
  const f4v z4 = {0.f, 0.f, 0.f, 0.f};
  float* xm = reinterpret_cast<float*>(smem + XMOFF);   // [ROWS][130] f32
  const int bb_ = blockIdx.x;

  // ===== phase 0: fused OPROJ + residual + LN1 -> xm (LDS) =====
  {
    // stage posmap once (768/384 distinct values vs ~16K redundant gathers)
    for (int p = tid; p < NH*ROWS; p += NT){
      int h = p >> RSH, r = p & (ROWS-1);
      sPos[h*ROWS + r] = posmapp[((size_t)(bb_*NH + h))*L0 + r];
    }
    __syncthreads();
    u16* sX = smem;                                     // [ROWS][136] bf16
    for (int p = tid; p < ROWS*128; p += NT){
      int r = p >> 7, c = p & 127;
      u16 v16 = 0;
      if (c < DM){
        int h = c / DHd, d = c - h*DHd;
        int bh = bb_*NH + h;
        int pos = sPos[h*ROWS + r];
        v16 = (pos >= 0) ? updp[((size_t)bh*NTOP + pos)*DHd + d] : vmeanp[bh*DHd + d];
      }
      sX[r*136 + c] = v16;
    }
    __syncthreads();
    constexpr int MT = ROWS/16;                         // 8 or 4 m-tiles
    constexpr int NGRP = 16/MT;                         // 2 or 4 groups
    constexpr int NTILE = 8/NGRP;                       // 4 or 2 n-tiles/wave
    const int m0o = (wave % MT)*16;
    const int nb0 = (wave / MT)*NTILE;
    const u16* wol = wo + (size_t)layer*16384;
    f4v oacc[NTILE];
    #pragma unroll
    for (int t = 0; t < NTILE; t++) oacc[t] = z4;
    #pragma unroll
    for (int ks = 0; ks < 4; ks++){
      s8v a = *reinterpret_cast<const s8v*>(sX + (m0o + l15)*136 + ks*32 + quad*8);
      const u16* wbp = wol + (size_t)l15*128 + ks*32 + quad*8;
      #pragma unroll
      for (int t = 0; t < NTILE; t++){
        s8v bfr = *reinterpret_cast<const s8v*>(wbp + (size_t)(nb0 + t)*16*128);
        oacc[t] = __builtin_amdgcn_mfma_f32_16x16x32_bf16(a, bfr, oacc[t], 0, 0, 0);
      }
    }
    __syncthreads();
    float* sOf = reinterpret_cast<float*>(smem);        // [ROWS][129]
    #pragma unroll
    for (int t = 0; t < NTILE; t++){
      int col = (nb0 + t)*16 + l15;
      #pragma unroll
      for (int r = 0; r < 4; r++)
        sOf[(m0o + quad*4 + r)*129 + col] = oacc[t][r];
    }
    __syncthreads();
    const float* obl = obp + (size_t)layer*DM;
    for (int p = tid; p < ROWS*DM; p += NT){
      int r = p / DM, c = p - r*DM;
      sOf[r*129 + c] += xres[((size_t)bb_*ROWS + r)*DM + c] + obl[c];
    }
    __syncthreads();
    ln_stats<ROWS>(sOf, prs, smean, srstd, tid);
    const float* l1gl = l1g + (size_t)layer*DM;
    const float* l1bl = l1b + (size_t)layer*DM;
    for (int p = tid; p < ROWS*DM; p += NT){
      int r = p / DM, c = p - r*DM;
      xm[r*130 + c] = (sOf[r*129 + c] - smean[r])*srstd[r]*l1gl[c] + l1bl[c];
    }
    __syncthreads();
  }

  s8v aX[MT2][4];
  #pragma unroll
  for (int mt = 0; mt < MT2; mt++){
    #pragma unroll
    for (int ks = 0; ks < 4; ks++){
      #pragma unroll
      for (int jj2 = 0; jj2 < 8; jj2++){
        int c = ks*32 + quad*8 + jj2;
        float v = (c < DM) ? xm[(rowb + mt*16 + l15)*130 + c] : 0.f;
        aX[mt][ks][jj2] = (short)f2bf(v);
      }
    }
  }
  stage_w1_p(w1t, 0, wA0, tid);
  stage_w2_p(w2t, 0, wB0, tid);

  const float* b1l = b1 + (size_t)layer*DFF;
  f4v acc2[MT2][2];
  #pragma unroll
  for (int mt = 0; mt < MT2; mt++){ acc2[mt][0] = z4; acc2[mt][1] = z4; }

  for (int j = 0; j < 32; j++){
    u16* wAcur = (j & 1) ? wA1 : wA0;
    u16* wAnxt = (j & 1) ? wA0 : wA1;
    u16* wBcur = (j & 1) ? wB1 : wB0;
    u16* wBnxt = (j & 1) ? wB0 : wB1;
    __syncthreads();
    if (j < 31){
      stage_w1_p(w1t, j+1, wAnxt, tid);
      stage_w2_p(w2t, j+1, wBnxt, tid);
    }
    // GEMM1: MR rows x 16 ff; 4 B-reads, 4*MT2 MFMA
    f4v acc1[MT2];
    #pragma unroll
    for (int mt = 0; mt < MT2; mt++) acc1[mt] = z4;
    {
      int nloc = ng*16 + l15;
      #pragma unroll
      for (int ks = 0; ks < 4; ks++){
        int cg = (ks*4 + quad) ^ (nloc & 7);
        s8v b = *reinterpret_cast<const s8v*>(wAcur + nloc*128 + cg*8);
        #pragma unroll
        for (int mt = 0; mt < MT2; mt++)
          acc1[mt] = __builtin_amdgcn_mfma_f32_16x16x32_bf16(aX[mt][ks], b, acc1[mt], 0, 0, 0);
      }
    }
    // bias + GELU + pack, write to mg-shared Y tile (swizzled)
    {
      int col = ng*16 + l15;
      float bv = b1l[j*64 + col];
      #pragma unroll
      for (int mt = 0; mt < MT2; mt++){
        float y0 = gelu_fast(acc1[mt][0] + bv);
        float y1 = gelu_fast(acc1[mt][1] + bv);
        float y2 = gelu_fast(acc1[mt][2] + bv);
        float y3 = gelu_fast(acc1[mt][3] + bv);
        unsigned p01 = cvt_pk_bf16(y0, y1);
        unsigned p23 = cvt_pk_bf16(y2, y3);
        int r0 = mt*16 + quad*4;
        sYg[yaddr(r0,     col)] = (u16)p01;
        sYg[yaddr(r0 + 1, col)] = (u16)(p01 >> 16);
        sYg[yaddr(r0 + 2, col)] = (u16)p23;
        sYg[yaddr(r0 + 3, col)] = (u16)(p23 >> 16);
      }
    }
    lgkm_barrier();
    // GEMM2: MR rows x 32 out-cols, K=64; MT2 A-reads x2 + 4 B-reads, 4*MT2 MFMA
    #pragma unroll
    for (int ks2 = 0; ks2 < 2; ks2++){
      int ga = ((ks2*4 + quad) ^ (l15 & 7)) << 3;
      s8v amt[MT2];
      #pragma unroll
      for (int mt = 0; mt < MT2; mt++)
        amt[mt] = *reinterpret_cast<const s8v*>(sYg + (mt*16 + l15)*64 + ga);
      #pragma unroll
      for (int t = 0; t < 2; t++){
        int nloc = ng*32 + t*16 + l15;
        int cg = (ks2*4 + quad) ^ (nloc & 7);
        s8v b = *reinterpret_cast<const s8v*>(wBcur + nloc*64 + cg*8);
        #pragma unroll
        for (int mt = 0; mt < MT2; mt++)
          acc2[mt][t] = __builtin_amdgcn_mfma_f32_16x16x32_bf16(amt[mt], b, acc2[mt][t], 0, 0, 0);
      }
    }
  }

  // ---- shared epilogue: acc2 -> sO, bias+residual(xm), ln2 stats ----
  __syncthreads();
  float* sO = reinterpret_cast<float*>(smem);
  #pragma unroll
  for (int mt = 0; mt < MT2; mt++)
    #pragma unroll
    for (int t = 0; t < 2; t++)
      #pragma unroll
      for (int r = 0; r < 4; r++)
        sO[(rowb + mt*16 + quad*4 + r)*129 + ng*32 + t*16 + l15] = acc2[mt][t][r];
  __syncthreads();
  const float* b2l = b2w + (size_t)layer*DM;
  for (int p = tid; p < ROWS*DM; p += NT){
    int r = p / DM, c = p - r*DM;
    sO[r*129 + c] += b2l[c] + xm[r*130 + c];
  }
  __syncthreads();
  ln_stats<ROWS>(sO, prs, smean, srstd, tid);
  const float* gl = g  + (size_t)layer*DM;
  const float* bl = bb + (size_t)layer*DM;

  if constexpr (ROWS == 128){
    // ===== fused DISTILL: conv(378)+BN+ELU+maxpool -> out2 (X2) + sQ =====
    float rv[16];
    #pragma unroll
    for (int k = 0; k < 16; k++){
      int p = tid + k*1024;
      if (p < 128*DM){
        int r = p / DM, c = p - r*DM;
        rv[k] = (sO[r*129 + c] - smean[r])*srstd[r]*gl[c] + bl[c];
      } else rv[k] = 0.f;
    }
    __syncthreads();
    u16* sAd = smem;
    #pragma unroll
    for (int k = 0; k < 16; k++){
      int p = tid + k*1024;
      if (p < 128*DM){
        int r = p / DM, c = p - r*DM;
        u16 bv = f2bf(rv[k]);
        sAd[((r + 1) & 127)*392 + c] = bv;
        sAd[r*392 + 126 + c] = bv;
        sAd[((r + 127) & 127)*392 + 252 + c] = bv;
      }
    }
    if (tid < 768){ int row = tid / 6, c2 = tid - row*6; sAd[row*392 + 378 + c2] = 0; }
    __syncthreads();
    const int mrow  = (wave & 7) * 16;
    const int tbase = (wave >> 3) * 4;
    f4v dac[4];
    dac[0]=z4; dac[1]=z4; dac[2]=z4; dac[3]=z4;
    for (int ks = 0; ks < 12; ks++){
      s8v a = *reinterpret_cast<const s8v*>(sAd + (mrow + l15)*392 + ks*32 + quad*8);
      const u16* wbp = wdist + (size_t)l15*384 + ks*32 + quad*8;
      #pragma unroll
      for (int t = 0; t < 4; t++){
        s8v bfr = *reinterpret_cast<const s8v*>(wbp + (size_t)(tbase + t)*16*384);
        dac[t] = __builtin_amdgcn_mfma_f32_16x16x32_bf16(a, bfr, dac[t], 0, 0, 0);
      }
    }
    __syncthreads();
    float* zsh = reinterpret_cast<float*>(smem);
    const float bnscale = 1.f / sqrtf(1.f + 1e-5f);
    #pragma unroll
    for (int t = 0; t < 4; t++){
      int co = (tbase + t)*16 + l15;
      if (co < DM){
        float cb = e1[co];
        float gg = e2[co] * bnscale, bv = e3[co];
        #pragma unroll
        for (int r = 0; r < 4; r++){
          int row = mrow + quad*4 + r;
          float z = (dac[t][r] + cb)*gg + bv;
          z = (z > 0.f) ? z : (__expf(z) - 1.f);
          zsh[row*130 + co] = z;
        }
      }
    }
    __syncthreads();
    // maxpool -> out2 (X2) AND sQ bf16 tile (reuses dead xm region)
    u16* sQ = smem + XMOFF;
    for (int p = tid; p < 64*128; p += 1024){
      int jj = p >> 7, co = p & 127;
      float best = 0.f;
      if (co < DM){
        best = zsh[(2*jj)*130 + co];
        if (jj > 0) best = fmaxf(best, zsh[(2*jj - 1)*130 + co]);
        best = fmaxf(best, zsh[(2*jj + 1)*130 + co]);
        out2[((size_t)bb_*64 + jj)*DM + co] = best;
      }
      sQ[jj*136 + co] = f2bf(best);
    }
    __syncthreads();
    // ===== fused QKV (L=64): M=64, N=384, K=128 from sQ =====
    {
      const int mq  = wave & 3;        // 4 m-tiles (64 rows)
      const int ngq = wave >> 2;       // 4 groups x 6 n-tiles
      f4v qa[6];
      #pragma unroll
      for (int t = 0; t < 6; t++) qa[t] = z4;
      #pragma unroll
      for (int ks = 0; ks < 4; ks++){
        s8v a = *reinterpret_cast<const s8v*>(sQ + (mq*16 + l15)*136 + ks*32 + quad*8);
        const u16* wbq = wqkv1 + (size_t)l15*128 + ks*32 + quad*8;
        #pragma unroll
        for (int t = 0; t < 6; t++){
          int nt = ngq*6 + t;
          s8v b = *reinterpret_cast<const s8v*>(wbq + (size_t)nt*16*128);
          qa[t] = __builtin_amdgcn_mfma_f32_16x16x32_bf16(a, b, qa[t], 0, 0, 0);
        }
      }
      #pragma unroll
      for (int t = 0; t < 6; t++){
        int col = (ngq*6 + t)*16 + l15;
        float bv = qb1[col];
        #pragma unroll
        for (int r = 0; r < 4; r++){
          int row = mq*16 + quad*4 + r;
          if (col < 256){
            qkvout[((size_t)bb_*64 + row)*256 + col] = qa[t][r] + bv;
          } else {
            int c = col - 256;
            if (c < DM){
              int h = c / DHd, d = c - h*DHd;
              vtout[((size_t)(bb_*NH + h)*DHd + d)*64 + row] = f2bf(qa[t][r] + bv);
            }
          }
        }
      }
    }
  } else {
    // ===== fused FINAL: ln2 in-place, enc-LN + fc -> d_out =====
    for (int p = tid; p < ROWS*DM; p += NT){
      int r = p / DM, c = p - r*DM;
      sO[r*129 + c] = (sO[r*129 + c] - smean[r])*srstd[r]*gl[c] + bl[c];
    }
    __syncthreads();
    ln_stats<ROWS>(sO, prs, smean, srstd, tid);
    // fc: 8 threads per col (partial sums over 8 l's each), then reduce
    {
      int col = tid >> 3, part = tid & 7;
      float s = 0.f;
      if (col < DM){
        float gv = e1[col], bv2 = e2[col];
        #pragma unroll
        for (int l = part*8; l < part*8 + 8; l++){
          float xn = (sO[l*129 + col] - smean[l])*srstd[l]*gv + bv2;
          s += xn * e3[l];
        }
      }
      prs[tid] = s;
    }
    __syncthreads();
    if (tid < DM){
      float acc = e4[0];
      #pragma unroll
      for (int p = 0; p < 8; p++) acc += prs[tid*8 + p];
      out2[(size_t)bb_*DM + tid] = acc;
    }
  }
}

// ---------------- host launcher ----------------
extern "C" void kernel_launch(void* const* d_in, const int* in_sizes, int n_in,
                              void* d_out, int out_size, void* d_ws, size_t ws_size,
                              hipStream_t stream) {
  fp x_enc   = (fp)d_in[0];
  fp x_mark  = (fp)d_in[1];
  fp token_w = (fp)d_in[2];
  fp time_w  = (fp)d_in[3];
  fp time_b  = (fp)d_in[4];
  fp od_fc_w = (fp)d_in[5];
  fp od_bn_g = (fp)d_in[6];
  fp od_bn_b = (fp)d_in[7];
  fp od_ch_w = (fp)d_in[8];
  fp od_ch_b = (fp)d_in[9];
  fp od_fil_w= (fp)d_in[10];
  fp od_fil_b= (fp)d_in[11];
  fp od_sp_w = (fp)d_in[12];
  fp od_sp_b = (fp)d_in[13];
  fp od_ker_w= (fp)d_in[14];
  fp od_ker_b= (fp)d_in[15];
  fp od_wt   = (fp)d_in[16];
  fp q_w = (fp)d_in[17]; fp q_b = (fp)d_in[18];
  fp k_w = (fp)d_in[19]; fp k_b = (fp)d_in[20];
  fp v_w = (fp)d_in[21]; fp v_b = (fp)d_in[22];
  fp o_w = (fp)d_in[23]; fp o_b = (fp)d_in[24];
  fp f1w = (fp)d_in[25]; fp f1b = (fp)d_in[26];
  fp f2w = (fp)d_in[27]; fp f2b = (fp)d_in[28];
  fp ln1g= (fp)d_in[29]; fp ln1b= (fp)d_in[30];
  fp ln2g= (fp)d_in[31]; fp ln2b= (fp)d_in[32];
  fp cl_w= (fp)d_in[33]; fp cl_b= (fp)d_in[34];
  fp clbg= (fp)d_in[35]; fp clbb= (fp)d_in[36];
  fp elng= (fp)d_in[37]; fp elnb= (fp)d_in[38];
  fp fc_w= (fp)d_in[39]; fp fc_b= (fp)d_in[40];

  // ---- workspace layout (float units) ----
  const size_t OFF_IDX0 = 0;
  const size_t OFF_IDX1 = OFF_IDX0 + 3200;
  const size_t OFF_CH   = OFF_IDX1 + 1600;
  const size_t OFF_FIL  = OFF_CH  + (size_t)NB*DE;
  const size_t OFF_SP   = OFF_FIL + (size_t)NB*DE;
  const size_t OFF_KER  = OFF_SP  + (size_t)NB*4;
  const size_t OFF_VM   = OFF_KER + (size_t)NB*4;
  const size_t OFF_POS  = OFF_VM  + (size_t)NB*NH*DHd;
  const size_t OFF_UPD  = OFF_POS + (size_t)NB*NH*L0;
  const size_t OFF_STOP = OFF_UPD + (size_t)NB*NH*NTOP*DHd;
  const size_t OFF_WTS  = (OFF_STOP + (size_t)NB*NH*NTOP + 255) & ~(size_t)255;
  const size_t WTS_FLOATS = (2*262144 + 2*262144 + 2*49152 + 2*16384 + 49152 + 32768)/2 + 2*384;
  const size_t OFF_BIG  = (OFF_WTS + WTS_FLOATS + 255) & ~(size_t)255;
  const size_t SBUF     = (size_t)NB*DE*L0;
  const size_t TOTAL    = OFF_BIG + 4*SBUF;

  if (ws_size < TOTAL*sizeof(float)){
    hipLaunchKernelGGL(k_zero, dim3((out_size+255)/256), dim3(256), 0, stream,
                       (float*)d_out, out_size);
    return;
  }

  float* ws = (float*)d_ws;
  int* idx0 = (int*)(ws + OFF_IDX0);
  int* idx1 = (int*)(ws + OFF_IDX1);
  u16* vme  = (u16*)(ws + OFF_VM);
  int* posm  = (int*)(ws + OFF_POS);
  u16* updb  = (u16*)(ws + OFF_UPD);
  u16* w1tb  = (u16*)(ws + OFF_WTS);
  u16* w2tb  = w1tb + 2*262144;
  u16* wqkvb = w2tb + 2*262144;
  u16* wob   = wqkvb + 2*49152;
  u16* wdistb= wob + 2*16384;
  u16* wembb = wdistb + 49152;
  float* qkvbias = (float*)(wembb + 32768);

  // big buffers: X | QKV | X2 | VT(bf16, reinterpreted region)
  float* X    = ws + OFF_BIG;
  float* QKV  = X + SBUF;
  float* X2   = X + 2*SBUF;
  u16*   VTb  = (u16*)(X + 3*SBUF);

  hipLaunchKernelGGL(k_prep, dim3(1092), dim3(256), 0, stream,
                     idx0, idx1, token_w, cl_w, q_w, q_b, k_w, k_b, v_w, v_b, o_w,
                     wembb, wdistb, wqkvb, wob, qkvbias,
                     f1w, f2w, w1tb, w2tb);
  hipLaunchKernelGGL(k_front, dim3(NB), dim3(256), 0, stream,
                     x_enc, x_mark, wembb, time_w, time_b,
                     od_fc_w, od_bn_g, od_bn_b, od_ch_w, od_ch_b, od_fil_w, od_fil_b,
                     od_sp_w, od_sp_b, od_ker_w, od_ker_b, od_wt, X);

  // ----- layer 0 (L=128) -----
  hipLaunchKernelGGL(k_qkv_mfma, dim3(NB*L0/64), dim3(256), 0, stream,
                     X, wqkvb, qkvbias, QKV, VTb, 128, 7, 127);
  hipLaunchKernelGGL(k_attn, dim3(NB*NH), dim3(128), 0, stream,
                     QKV, VTb, idx0, L0, posm, vme, updb);
  // FFN L0: fused oproj(L0) head + loop + distil tail + QKV(L1) tail
  hipLaunchKernelGGL((k_ffn<128>), dim3(NB), dim3(1024), 0, stream,
                     w1tb, w2tb, f1b, f2b, ln2g, ln2b, 0,
                     wdistb, cl_b, clbg, clbb, cl_b,
                     X, vme, posm, updb, wob, o_b, ln1g, ln1b,
                     wqkvb + 49152, qkvbias + 384, QKV, VTb,
                     X2);

  // ----- layer 1 (L=64) -----
  hipLaunchKernelGGL(k_attn, dim3(NB*NH), dim3(128), 0, stream,
                     QKV, VTb, idx1, 64, posm, vme, updb);
  // FFN L1: fused oproj(L1) head + 16-wave loop + final tail -> d_out
  hipLaunchKernelGGL((k_ffn<64>), dim3(256), dim3(1024), 0, stream,
                     w1tb + 262144, w2tb + 262144, f1b, f2b, ln2g, ln2b, 1,
                     wdistb, elng, elnb, fc_w, fc_b,
                     X2, vme, posm, updb, wob, o_b, ln1g, ln1b,
                     wqkvb + 49152, qkvbias + 384, QKV, VTb,
                     (float*)d_out);
  (void)in_sizes; (void)n_in; (void)out_size; (void)ws_size;
}

// Round 16
// 502.609 us; speedup vs baseline: 1.0708x; 1.0708x over previous
//
#include <hip/hip_runtime.h>
#include <math.h>

// Problem dims
#define NB 256
#define DM 126       // D_MODEL
#define DE 128       // D_EMB
#define NH 6
#define DHd 21
#define DFF 2048
#define CIN 75
#define L0 128
#define NTOP 25

#ifndef IDX_MODE
#define IDX_MODE 0
#endif

typedef const float* fp;
typedef unsigned short u16;
typedef short s8v __attribute__((ext_vector_type(8)));
typedef float f4v __attribute__((ext_vector_type(4)));

__device__ __forceinline__ u16 f2bf(float x){
  unsigned u = __float_as_uint(x);
  unsigned r = (u + 0x7FFFu + ((u >> 16) & 1u)) >> 16;
  return (u16)r;
}
__device__ __forceinline__ float bf2f(u16 v){
  unsigned uu = ((unsigned)v) << 16;
  return __uint_as_float(uu);
}

__device__ __forceinline__ void gld_lds16(const u16* g, u16* l){
  __builtin_amdgcn_global_load_lds((const __attribute__((address_space(1))) unsigned int*)(const void*)g,
                                   (__attribute__((address_space(3))) unsigned int*)(void*)l,
                                   16, 0, 0);
}

// pack 2 f32 -> 2 bf16 (RNE) in one VALU op
__device__ __forceinline__ unsigned cvt_pk_bf16(float lo, float hi){
  unsigned r;
  asm("v_cvt_pk_bf16_f32 %0, %1, %2" : "=v"(r) : "v"(lo), "v"(hi));
  return r;
}

__device__ __forceinline__ void tf2(unsigned k0, unsigned k1, unsigned x0, unsigned x1,
                                    unsigned &o0, unsigned &o1){
  unsigned ks2 = k0 ^ k1 ^ 0x1BD11BDAu;
  x0 += k0; x1 += k1;
  #define RR(r) { x0 += x1; x1 = (x1 << (r)) | (x1 >> (32 - (r))); x1 ^= x0; }
  RR(13) RR(15) RR(26) RR(6)
  x0 += k1;  x1 += ks2 + 1u;
  RR(17) RR(29) RR(16) RR(24)
  x0 += ks2; x1 += k0 + 2u;
  RR(13) RR(15) RR(26) RR(6)
  x0 += k0;  x1 += k1 + 3u;
  RR(17) RR(29) RR(16) RR(24)
  x0 += k1;  x1 += ks2 + 4u;
  RR(13) RR(15) RR(26) RR(6)
  x0 += ks2; x1 += k0 + 5u;
  #undef RR
  o0 = x0; o1 = x1;
}

// ---------------- fallback: zero output (ws too small diagnostic) ----------------
__global__ __launch_bounds__(256) void k_zero(float* out, int n){
  int i = blockIdx.x*256 + threadIdx.x;
  if (i < n) out[i] = 0.f;
}

// ============================================================================
// MERGED prep: idx (block 0) + wprep (blocks 1..835) + wtrans (836..1091).
// ============================================================================
__global__ __launch_bounds__(256) void k_prep(int* idx0, int* idx1,
                                              fp token_w, fp clw,
                                              fp qw, fp qb, fp kw, fp kb, fp vw, fp vb, fp ow,
                                              u16* wemb, u16* wdist, u16* wqkv, u16* wo,
                                              float* qbias,
                                              fp f1w, fp f2w, u16* w1t, u16* w2t){
  __shared__ u16 sT[64*65];
  const int blk = blockIdx.x;
  const int tid = threadIdx.x;
  if (blk == 0){
    unsigned a0,a1,c0,c1;
    tf2(0u,42u, 0u,0u, a0,a1);
    tf2(0u,42u, 0u,1u, c0,c1);
    for (int f = tid; f < 3200; f += 256){
      unsigned y0,y1;
#if IDX_MODE==0
      tf2(a0,a1, 0u, (unsigned)(3200+f), y0,y1); idx0[f] = (int)(y1 & 127u);
#elif IDX_MODE==1
      tf2(a0,a1, 0u, (unsigned)(3200+f), y0,y1); idx0[f] = (int)(y0 & 127u);
#elif IDX_MODE==2
      tf2(a0,a1, (unsigned)f, (unsigned)(3200+f), y0,y1); idx0[f] = (int)(y1 & 127u);
#else
      tf2(a0,a1, (unsigned)f, (unsigned)(3200+f), y0,y1); idx0[f] = (int)(y0 & 127u);
#endif
    }
    for (int f = tid; f < 1600; f += 256){
      unsigned y0,y1;
#if IDX_MODE==0
      tf2(c0,c1, 0u, (unsigned)(1600+f), y0,y1); idx1[f] = (int)(y1 & 63u);
#elif IDX_MODE==1
      tf2(c0,c1, 0u, (unsigned)(1600+f), y0,y1); idx1[f] = (int)(y0 & 63u);
#elif IDX_MODE==2
      tf2(c0,c1, (unsigned)f, (unsigned)(1600+f), y0,y1); idx1[f] = (int)(y1 & 63u);
#else
      tf2(c0,c1, (unsigned)f, (unsigned)(1600+f), y0,y1); idx1[f] = (int)(y0 & 63u);
#endif
    }
    return;
  }
  if (blk <= 835){
    int i = (blk - 1)*256 + tid;
    if (i < 32768){
      int n = i >> 8, k = i & 255;
      float v = 0.f;
      if (k < 225){ int q = k/75, c = k - q*75; v = token_w[(size_t)n*225 + c*3 + q]; }
      wemb[i] = f2bf(v);
      return;
    }
    i -= 32768;
    if (i < 49152){
      int n = i / 384, k = i - n*384;
      float v = 0.f;
      if (n < DM && k < 378){ int q = k/126, ci = k - q*126; v = clw[((size_t)n*DM + ci)*3 + q]; }
      wdist[i] = f2bf(v);
      return;
    }
    i -= 49152;
    if (i < 2*49152){
      int layer = i / 49152, jj = i - layer*49152;
      int n = jj >> 7, k = jj & 127;
      int sec = n >> 7, nn = n & 127;
      const float* w = (sec == 0) ? qw : ((sec == 1) ? kw : vw);
      float v = (nn < DM && k < DM) ? w[((size_t)layer*DM + k)*DM + nn] : 0.f;
      wqkv[(size_t)layer*49152 + jj] = f2bf(v);
      return;
    }
    i -= 2*49152;
    if (i < 2*16384){
      int layer = i / 16384, jj = i - layer*16384;
      int n = jj >> 7, k = jj & 127;
      float v = (n < DM && k < DM) ? ow[(size_t)layer*DM*DM + k*DM + n] : 0.f;
      wo[(size_t)layer*16384 + jj] = f2bf(v);
      return;
    }
    i -= 2*16384;
    if (i < 768){
      int layer = i / 384, n = i - layer*384;
      int sec = n >> 7, nn = n & 127;
      const float* bp = (sec == 0) ? qb : ((sec == 1) ? kb : vb);
      qbias[(size_t)layer*384 + n] = (nn < DM) ? bp[layer*DM + nn] : 0.f;
    }
    return;
  }
  // ---- wtrans: coalesced LDS-tiled transposes of f1w/f2w ----
  {
    const int t = blk - 836;
    const int lane = tid & 63, rg = tid >> 6;
    if (t < 128){
      int layer = t >> 6, rem = t & 63;
      int kt = rem >> 5, nt = rem & 31;
      #pragma unroll
      for (int rr = 0; rr < 16; rr++){
        int row = rg + rr*4;
        int k = kt*64 + row;
        float v = (k < DM) ? f1w[((size_t)layer*DM + k)*DFF + nt*64 + lane] : 0.f;
        sT[row*65 + lane] = f2bf(v);
      }
      __syncthreads();
      #pragma unroll
      for (int rr = 0; rr < 16; rr++){
        int nrow = rg + rr*4;
        int n_glob = nt*64 + nrow;
        w1t[(size_t)layer*262144 + (size_t)n_glob*128 + kt*64 + lane] = sT[lane*65 + nrow];
      }
    } else {
      int t2 = t - 128;
      int layer = t2 >> 6, rem = t2 & 63;
      int nt = rem >> 5, ft = rem & 31;
      #pragma unroll
      for (int rr = 0; rr < 16; rr++){
        int row = rg + rr*4;
        int f = ft*64 + row;
        int n = nt*64 + lane;
        float v = (n < DM) ? f2w[((size_t)layer*DFF + f)*DM + n] : 0.f;
        sT[row*65 + lane] = f2bf(v);
      }
      __syncthreads();
      #pragma unroll
      for (int rr = 0; rr < 16; rr++){
        int nrow = rg + rr*4;
        int n_glob = nt*64 + nrow;
        w2t[(size_t)layer*262144 + (size_t)n_glob*2048 + ft*64 + lane] = sT[lane*65 + nrow];
      }
    }
  }
}

// ============================================================================
// FUSED front: token-embed(conv K=225 + pos + time) -> attn scalars -> ODConv.
// ============================================================================
__global__ __launch_bounds__(256) void k_front(fp x_enc, fp x_mark, const u16* wemb,
                                               fp time_w, fp time_b,
                                               fp fcw, fp bng, fp bnb,
                                               fp chw, fp chb, fp filw, fp filb,
                                               fp spw, fp spb, fp kerw, fp kerb,
                                               fp odw, float* xout){
  __shared__ __align__(16) u16 smem[71232];
  u16*   sXT = smem;
  u16*   sW  = smem + 17680;
  u16*   sA  = smem + 17680;
  float* sE  = reinterpret_cast<float*>(smem + 17680);
  float* red = reinterpret_cast<float*>(smem + 69904);
  float* gap = reinterpret_cast<float*>(smem + 70416);
  float* aAct= reinterpret_cast<float*>(smem + 70672);
  float* sch = reinterpret_cast<float*>(smem + 70704);
  float* sfil= reinterpret_cast<float*>(smem + 70960);
  float* ssp = reinterpret_cast<float*>(smem + 71216);
  float* sker= reinterpret_cast<float*>(smem + 71224);
  const int tid = threadIdx.x;
  const int wave = tid >> 6, lane = tid & 63, quad = lane >> 4, l15 = lane & 15;
  const int b = blockIdx.x;
  const f4v z4 = {0.f,0.f,0.f,0.f};
  const int mBase = wave * 32;

  // ---- phase 1: conv input staging ----
  {
    const float4* xb = reinterpret_cast<const float4*>(x_enc + (size_t)b*L0*CIN);
    for (int p4 = tid; p4 < (L0*CIN)/4; p4 += 256){
      float4 v4 = xb[p4];
      float vv[4] = {v4.x, v4.y, v4.z, v4.w};
      int e0 = p4*4;
      #pragma unroll
      for (int j = 0; j < 4; j++){
        int e = e0 + j;
        int sr = e / CIN, c = e - sr*CIN;
        u16 bv = f2bf(vv[j]);
        sA[((sr + 1) & 127)*264 + c] = bv;
        sA[sr*264 + 75 + c] = bv;
        sA[((sr + 127) & 127)*264 + 150 + c] = bv;
      }
    }
    for (int p = tid; p < 128*31; p += 256){
      int row = p / 31, c2 = p - row*31;
      sA[row*264 + 225 + c2] = 0;
    }
  }
  __syncthreads();
  // ---- phase 1b: MFMA + epilogue -> sE ----
  {
    f4v acc[2][8];
    #pragma unroll
    for (int m = 0; m < 2; m++)
      #pragma unroll
      for (int t = 0; t < 8; t++) acc[m][t] = z4;
    for (int ks = 0; ks < 8; ks++){
      s8v a0 = *reinterpret_cast<const s8v*>(sA + (mBase + l15)*264 + ks*32 + quad*8);
      s8v a1 = *reinterpret_cast<const s8v*>(sA + (mBase + 16 + l15)*264 + ks*32 + quad*8);
      const u16* wb = wemb + (size_t)l15*256 + ks*32 + quad*8;
      #pragma unroll
      for (int t = 0; t < 8; t++){
        s8v bfr = *reinterpret_cast<const s8v*>(wb + (size_t)t*16*256);
        acc[0][t] = __builtin_amdgcn_mfma_f32_16x16x32_bf16(a0, bfr, acc[0][t], 0, 0, 0);
        acc[1][t] = __builtin_amdgcn_mfma_f32_16x16x32_bf16(a1, bfr, acc[1][t], 0, 0, 0);
      }
    }
    float divc[8], tw0c[8], tw1c[8], tw2c[8], tbc[8];
    #pragma unroll
    for (int t = 0; t < 8; t++){
      int col = t*16 + l15;
      int i2 = col >> 1;
      divc[t] = __expf((float)(2*i2) * (-9.210340371976184f / 128.f));
      tw0c[t] = time_w[col]; tw1c[t] = time_w[128 + col]; tw2c[t] = time_w[256 + col];
      tbc[t] = time_b[col];
    }
    #pragma unroll
    for (int m = 0; m < 2; m++){
      #pragma unroll
      for (int r = 0; r < 4; r++){
        int row = mBase + m*16 + quad*4 + r;
        const float* mk = x_mark + ((size_t)b*L0 + row)*3;
        float m0v = mk[0], m1v = mk[1], m2v = mk[2];
        #pragma unroll
        for (int t = 0; t < 8; t++){
          int col = t*16 + l15;
          float ang = (float)row * divc[t];
          float pe = (col & 1) ? __cosf(ang) : __sinf(ang);
          float tm = m0v*tw0c[t] + m1v*tw1c[t] + m2v*tw2c[t] + tbc[t];
          sE[row*132 + col] = acc[m][t][r] + pe + tm;
        }
      }
    }
  }
  __syncthreads();
  // ---- phase 2: attention scalars ----
  {
    int col = tid & 127, half = tid >> 7;
    float s = 0.f;
    for (int r = 0; r < 64; r++) s += sE[(half*64 + r)*132 + col];
    red[tid] = s;
  }
  __syncthreads();
  if (tid < 128) gap[tid] = (red[tid] + red[tid + 128]) * (1.f/128.f);
  __syncthreads();
  if (tid < 16){
    float acc = 0.f;
    for (int e = 0; e < DE; e++) acc += gap[e]*fcw[e*16 + tid];
    acc = acc * (bng[tid] / sqrtf(1.f + 1e-5f)) + bnb[tid];
    aAct[tid] = fmaxf(acc, 0.f);
  }
  __syncthreads();
  if (tid < 128){
    float accc = 0.f, accf = 0.f;
    for (int c = 0; c < 16; c++){ accc += aAct[c]*chw[c*DE + tid]; accf += aAct[c]*filw[c*DE + tid]; }
    sch[tid]  = 1.f/(1.f + __expf(-(accc + chb[tid])));
    sfil[tid] = 1.f/(1.f + __expf(-(accf + filb[tid])));
  } else if (tid < 131){
    int t = tid - 128;
    float acc = 0.f;
    for (int c = 0; c < 16; c++) acc += aAct[c]*spw[c*3 + t];
    ssp[t] = 1.f/(1.f + __expf(-(acc + spb[t])));
  } else if (tid == 132){
    float v[4]; float mx = -1e30f;
    for (int n = 0; n < 4; n++){
      float acc = 0.f;
      for (int c = 0; c < 16; c++) acc += aAct[c]*kerw[c*4 + n];
      v[n] = acc + kerb[n]; mx = fmaxf(mx, v[n]);
    }
    float ss = 0.f;
    for (int n = 0; n < 4; n++){ v[n] = __expf(v[n]-mx); ss += v[n]; }
    for (int n = 0; n < 4; n++) sker[n] = v[n]/ss;
  }
  __syncthreads();
  // ---- phase 3a: sXT = emb * ch ----
  for (int p = tid; p < 130*128; p += 256){
    int l = p >> 7, i = p & 127;
    float v = (l < 128) ? sE[l*132 + i]*sch[i] : 0.f;
    sXT[l*136 + i] = f2bf(v);
  }
  __syncthreads();
  // ---- phase 3b: aggregate weights -> sW ----
  {
    float kr0 = sker[0], kr1 = sker[1], kr2 = sker[2], kr3 = sker[3];
    float spq[3]; spq[0] = ssp[0]; spq[1] = ssp[1]; spq[2] = ssp[2];
    const float4* od4 = (const float4*)odw;
    for (int p4 = tid; p4 < 128*384/4; p4 += 256){
      float4 w0 = od4[p4];
      float4 w1 = od4[12288 + p4];
      float4 w2 = od4[24576 + p4];
      float4 w3 = od4[36864 + p4];
      float vv[4] = { kr0*w0.x + kr1*w1.x + kr2*w2.x + kr3*w3.x,
                      kr0*w0.y + kr1*w1.y + kr2*w2.y + kr3*w3.y,
                      kr0*w0.z + kr1*w1.z + kr2*w2.z + kr3*w3.z,
                      kr0*w0.w + kr1*w1.w + kr2*w2.w + kr3*w3.w };
      int e0 = p4*4;
      #pragma unroll
      for (int j = 0; j < 4; j++){
        int e = e0 + j;
        int o = e / 384, rem = e - o*384;
        int i = rem / 3, q = rem - i*3;
        sW[(q*128 + o)*136 + i] = f2bf(vv[j] * spq[q]);
      }
    }
  }
  __syncthreads();
  // ---- phase 3c: ODConv MFMA + gated store ----
  {
    f4v acc[2][8];
    #pragma unroll
    for (int m = 0; m < 2; m++)
      #pragma unroll
      for (int t = 0; t < 8; t++) acc[m][t] = z4;
    for (int q = 0; q < 3; q++){
      const u16* wq = sW + q*128*136;
      #pragma unroll
      for (int ks = 0; ks < 4; ks++){
        s8v a0 = *reinterpret_cast<const s8v*>(wq + (mBase + l15)*136 + ks*32 + quad*8);
        s8v a1 = *reinterpret_cast<const s8v*>(wq + (mBase + 16 + l15)*136 + ks*32 + quad*8);
        #pragma unroll
        for (int t = 0; t < 8; t++){
          s8v bfr = *reinterpret_cast<const s8v*>(sXT + (t*16 + l15 + q)*136 + ks*32 + quad*8);
          acc[0][t] = __builtin_amdgcn_mfma_f32_16x16x32_bf16(a0, bfr, acc[0][t], 0, 0, 0);
          acc[1][t] = __builtin_amdgcn_mfma_f32_16x16x32_bf16(a1, bfr, acc[1][t], 0, 0, 0);
        }
      }
    }
    #pragma unroll
    for (int t = 0; t < 8; t++){
      int tt = t*16 + l15;
      if (tt < DM){
        #pragma unroll
        for (int m = 0; m < 2; m++){
          #pragma unroll
          for (int r = 0; r < 4; r++){
            int o = mBase + m*16 + quad*4 + r;
            xout[((size_t)b*DE + o)*DM + tt] = sfil[o] * acc[m][t][r];
          }
        }
      }
    }
  }
}

// ---------------- fused QKV GEMM (L0 only): Q,K -> qkv[M][256]; V -> vt(bf16) --
__global__ __launch_bounds__(256) void k_qkv_mfma(const float* xin, const u16* wqkv,
                                                  const float* qkvb, float* qkv,
                                                  u16* vt, int L, int lshift, int lmask){
  __shared__ __align__(16) u16 sX[64*136];
  const int tid = threadIdx.x;
  const int wave = tid >> 6, lane = tid & 63, quad = lane >> 4, l15 = lane & 15;
  const size_t rows0 = (size_t)blockIdx.x * 64;
  for (int p = tid; p < 64*128; p += 256){
    int r = p >> 7, c = p & 127;
    float v = (c < DM) ? xin[(rows0 + r)*DM + c] : 0.f;
    sX[r*136 + c] = f2bf(v);
  }
  __syncthreads();
  const f4v z4 = {0.f,0.f,0.f,0.f};
  f4v acc[24];
  #pragma unroll
  for (int t = 0; t < 24; t++) acc[t] = z4;
  const int m0 = wave * 16;
  #pragma unroll
  for (int ks = 0; ks < 4; ks++){
    s8v a = *reinterpret_cast<const s8v*>(sX + (m0 + l15)*136 + ks*32 + quad*8);
    const u16* wb = wqkv + (size_t)l15*128 + ks*32 + quad*8;
    #pragma unroll
    for (int t = 0; t < 24; t++){
      s8v b = *reinterpret_cast<const s8v*>(wb + (size_t)t*16*128);
      acc[t] = __builtin_amdgcn_mfma_f32_16x16x32_bf16(a, b, acc[t], 0, 0, 0);
    }
  }
  #pragma unroll
  for (int t = 0; t < 24; t++){
    int col = t*16 + l15;
    float bv = qkvb[col];
    if (col < 256){
      #pragma unroll
      for (int r = 0; r < 4; r++){
        int row = m0 + quad*4 + r;
        qkv[(rows0 + row)*256 + col] = acc[t][r] + bv;
      }
    } else {
      int c = col - 256;
      if (c < DM){
        int h = c / DHd, d = c - h*DHd;
        #pragma unroll
        for (int r = 0; r < 4; r++){
          int gr = (int)rows0 + m0 + quad*4 + r;
          int b = gr >> lshift, l = gr & lmask;
          vt[((size_t)(b*NH + h)*DHd + d)*L + l] = f2bf(acc[t][r] + bv);
        }
      }
    }
  }
}

// ============================================================================
// FUSED attention v2: one bh per 128-thread block, grid B*H.
// VT/upd/vmean bf16 (bit-identical: f2bf moved producer-side).
// ============================================================================
__global__ __launch_bounds__(128) void k_attn(const float* qkv, const u16* vt,
                                              const int* idx, int L,
                                              int* posmap, u16* vmean, u16* upd){
  __shared__ __align__(16) float sK[2816];
  __shared__ int sTop[32];
  const int tid = threadIdx.x;
  const int wave = tid >> 6, lane = tid & 63, quad = lane >> 4, l15 = lane & 15;
  const int bh = blockIdx.x;
  const int b = bh / NH, h = bh - b*NH;
  float* sM = sK + 2688;
  u16* sPb = reinterpret_cast<u16*>(sK);
  const float* qbase = qkv + (size_t)(b*L)*256 + h*DHd;
  const u16* vb = vt + (size_t)bh*DHd*L;
  const f4v z4 = {0.f,0.f,0.f,0.f};
  const int ntn = L >> 4;
  const int d0 = quad*8;
  const int mt = wave;

  for (int p = tid; p < L*DHd; p += 128){
    int l = p / DHd, d = p - l*DHd;
    sK[p] = qbase[(size_t)l*256 + 128 + d];
  }
  posmap[bh*L0 + tid] = -1;
  __syncthreads();
  if (tid < L){
    const int l = tid;
    const float* qg = qbase + (size_t)l*256;
    float qr[DHd];
    #pragma unroll
    for (int d = 0; d < DHd; d++) qr[d] = qg[d];
    float mx = -1e30f, sm = 0.f;
    #pragma unroll
    for (int u = 0; u < NTOP; u++){
      int kk = idx[l*NTOP + u];
      const float* kp = sK + kk*DHd;
      float acc = 0.f;
      #pragma unroll
      for (int d = 0; d < DHd; d++) acc += qr[d]*kp[d];
      mx = fmaxf(mx, acc); sm += acc;
    }
    sM[l] = mx - sm/(float)L;
  }
  __syncthreads();
  if (wave == 0){
    for (int it = 0; it < NTOP; it++){
      float bv = sM[lane]; int bi = lane;
      if (L == 128){
        float v1 = sM[lane + 64];
        if (v1 > bv){ bv = v1; bi = lane + 64; }
      }
      #pragma unroll
      for (int off = 32; off > 0; off >>= 1){
        float ov = __shfl_xor(bv, off);
        int   oi = __shfl_xor(bi, off);
        if (ov > bv || (ov == bv && oi < bi)){ bv = ov; bi = oi; }
      }
      if (lane == 0){
        sM[bi] = -1e30f;
        posmap[bh*L0 + bi] = it;
        sTop[it] = bi;
      }
    }
  }
  __syncthreads();

  s8v aq;
  {
    int uu = mt*16 + l15; if (uu >= NTOP) uu = 0;
    int r = sTop[uu];
    const float* qp = qbase + (size_t)r*256 + d0;
    #pragma unroll
    for (int j = 0; j < 8; j++) aq[j] = (short)f2bf(qp[j]);
  }
  f4v sc[8];
  for (int nt = 0; nt < ntn; nt++){
    const float* kp = sK + (size_t)(nt*16 + l15)*DHd + d0;
    s8v bb;
    #pragma unroll
    for (int j = 0; j < 8; j++) bb[j] = (d0 + j < DHd) ? (short)f2bf(kp[j]) : (short)0;
    sc[nt] = __builtin_amdgcn_mfma_f32_16x16x32_bf16(aq, bb, z4, 0, 0, 0);
  }
  __syncthreads();
  const float inv21 = 0.21821789023599236f;
  #pragma unroll
  for (int r4 = 0; r4 < 4; r4++){
    float mx = -1e30f;
    for (int nt = 0; nt < ntn; nt++) mx = fmaxf(mx, sc[nt][r4]*inv21);
    #pragma unroll
    for (int off = 1; off < 16; off <<= 1) mx = fmaxf(mx, __shfl_xor(mx, off));
    float e[8]; float ss = 0.f;
    for (int nt = 0; nt < ntn; nt++){ e[nt] = __expf(sc[nt][r4]*inv21 - mx); ss += e[nt]; }
    #pragma unroll
    for (int off = 1; off < 16; off <<= 1) ss += __shfl_xor(ss, off);
    float dn = 1.f / ss;
    int u = mt*16 + quad*4 + r4;
    for (int nt = 0; nt < ntn; nt++)
      sPb[u*136 + nt*16 + l15] = f2bf(e[nt]*dn);
  }
  if (wave == 1){
    u16 invL = f2bf(1.f/(float)L);
    for (int c = lane; c < L; c += 64) sPb[25*136 + c] = invL;
  }
  f4v pv[2];
  pv[0] = z4; pv[1] = z4;
  int kSteps = L >> 5;
  for (int ks = 0; ks < kSteps; ks++){
    #pragma unroll
    for (int nt = 0; nt < 2; nt++){
      int d = nt*16 + l15;
      s8v bb;
      if (d < DHd){
        const u16* vp = vb + (size_t)d*L + ks*32 + d0;   // bf16, 16B consecutive
        #pragma unroll
        for (int j = 0; j < 8; j++) bb[j] = (short)vp[j];
      } else {
        #pragma unroll
        for (int j = 0; j < 8; j++) bb[j] = (short)0;
      }
      s8v a = *reinterpret_cast<const s8v*>(sPb + (mt*16 + l15)*136 + ks*32 + d0);
      pv[nt] = __builtin_amdgcn_mfma_f32_16x16x32_bf16(a, bb, pv[nt], 0, 0, 0);
    }
  }
  #pragma unroll
  for (int nt = 0; nt < 2; nt++){
    #pragma unroll
    for (int r4 = 0; r4 < 4; r4++){
      int u = mt*16 + quad*4 + r4;
      int d = nt*16 + l15;
      if (d < DHd){
        if (u < NTOP)       upd[((size_t)bh*NTOP + u)*DHd + d] = f2bf(pv[nt][r4]);
        else if (u == NTOP) vmean[bh*DHd + d] = f2bf(pv[nt][r4]);
      }
    }
  }
}

// fast GELU in log2 domain
__device__ __forceinline__ float gelu_fast(float x){
  float x2 = x*x;
  float u = x * __builtin_fmaf(0.10295128f, x2, 2.30212056f);
  u = fminf(u, 126.f);
#if __has_builtin(__builtin_amdgcn_exp2f)
  float t = __builtin_amdgcn_exp2f(u);
#else
  float t = __expf(u * 0.69314718056f);
#endif
  return x * t * __builtin_amdgcn_rcpf(t + 1.f);
}

// ============================================================================
// FFN v11 (FINAL): template<ROWS>, NT=1024, 16 ACTIVE loop waves for BOTH
// layers. r15's parallel-LN/fc/posmap variant REGRESSED (+33 µs via LDS bank
// conflicts) and was reverted — serial-lane stats are covered by other waves
// for free at 16 waves/block; do not re-parallelize them.
// ============================================================================

__device__ __forceinline__ void stage_w1_p(const u16* w1t, int j, u16* buf, int p){
  int n = p >> 4, c = p & 15;
  int cg = c ^ (n & 7);
  gld_lds16(w1t + (((size_t)(j*64 + n)) << 7) + cg*8,
            buf + (size_t)((p >> 6) << 6)*8);
}
__device__ __forceinline__ void stage_w2_p(const u16* w2t, int j, u16* buf, int p){
  int n = p >> 3, c = p & 7;
  int cg = c ^ (n & 7);
  gld_lds16(w2t + (size_t)n*2048 + j*64 + cg*8,
            buf + (size_t)((p >> 6) << 6)*8);
}

// Y-tile address: [MR rows][64 K] u16, granule(8 u16 = 16B) XOR'd by row&7
__device__ __forceinline__ int yaddr(int row, int col){
  return row*64 + (((col >> 3) ^ (row & 7)) << 3) + (col & 7);
}

__device__ __forceinline__ void lgkm_barrier(){
  asm volatile("s_waitcnt lgkmcnt(0)" ::: "memory");
  __builtin_amdgcn_sched_barrier(0);
  __builtin_amdgcn_s_barrier();
  __builtin_amdgcn_sched_barrier(0);
}

template<int ROWS>
__global__ __launch_bounds__(1024) void k_ffn(const u16* w1t, const u16* w2t,
                                              fp b1, fp b2w, fp g, fp bb, int layer,
                                              const u16* wdist, fp e1, fp e2, fp e3, fp e4,
                                              const float* xres, const u16* vmeanp,
                                              const int* posmapp, const u16* updp,
                                              const u16* wo, fp obp, fp l1g, fp l1b,
                                              const u16* wqkv1, fp qb1, float* qkvout, u16* vtout,
                                              float* out2){
  constexpr int NT   = 1024;
  constexpr int MR   = ROWS/4;        // rows per mg-group (32 or 16)
  constexpr int MT2  = MR/16;         // m-tiles per wave in loop (2 or 1)
  constexpr int SYG  = ROWS*64;       // 4 mg Y tiles (u16): 8192 or 4096
  constexpr int XMOFF = SYG + 4*8192; // u16 offset of in-LDS xmid
  constexpr int TAILU = (ROWS == 128) ? 128*392 : 0;
  constexpr int XMEND = XMOFF + ROWS*130*2;
  constexpr int SMEMU = (XMEND > TAILU) ? XMEND : TAILU;
  __shared__ __align__(16) u16 smem[SMEMU];
  __shared__ float prs[2*ROWS];
  __shared__ float smean[ROWS], srstd[ROWS];
  u16* wA0 = smem + SYG;
  u16* wA1 = wA0 + 8192;
  u16* wB0 = wA1 + 8192;
  u16* wB1 = wB0 + 8192;
  const int tid  = threadIdx.x;
  const int wave = tid >> 6, lane = tid & 63, quad = lane >> 4, l15 = lane & 15;
  const int mg = wave >> 2, ng = wave & 3;
  const int rowb = mg * MR;
  u16* sYg = smem + mg*(MR*64);
  const f4v z4 = {0.f, 0.f, 0.f, 0.f};
  float* xm = reinterpret_cast<float*>(smem + XMOFF);   // [ROWS][130] f32
  const int bb_ = blockIdx.x;

  // ===== phase 0: fused OPROJ + residual + LN1 -> xm (LDS) =====
  {
    u16* sX = smem;                                     // [ROWS][136] bf16
    for (int p = tid; p < ROWS*128; p += NT){
      int r = p >> 7, c = p & 127;
      u16 v16 = 0;
      if (c < DM){
        int h = c / DHd, d = c - h*DHd;
        int bh = bb_*NH + h;
        int pos = posmapp[bh*L0 + r];
        v16 = (pos >= 0) ? updp[((size_t)bh*NTOP + pos)*DHd + d] : vmeanp[bh*DHd + d];
      }
      sX[r*136 + c] = v16;
    }
    __syncthreads();
    constexpr int MT = ROWS/16;                         // 8 or 4 m-tiles
    constexpr int NGRP = 16/MT;                         // 2 or 4 groups
    constexpr int NTILE = 8/NGRP;                       // 4 or 2 n-tiles/wave
    const int m0o = (wave % MT)*16;
    const int nb0 = (wave / MT)*NTILE;
    const u16* wol = wo + (size_t)layer*16384;
    f4v oacc[NTILE];
    #pragma unroll
    for (int t = 0; t < NTILE; t++) oacc[t] = z4;
    #pragma unroll
    for (int ks = 0; ks < 4; ks++){
      s8v a = *reinterpret_cast<const s8v*>(sX + (m0o + l15)*136 + ks*32 + quad*8);
      const u16* wbp = wol + (size_t)l15*128 + ks*32 + quad*8;
      #pragma unroll
      for (int t = 0; t < NTILE; t++){
        s8v bfr = *reinterpret_cast<const s8v*>(wbp + (size_t)(nb0 + t)*16*128);
        oacc[t] = __builtin_amdgcn_mfma_f32_16x16x32_bf16(a, bfr, oacc[t], 0, 0, 0);
      }
    }
    __syncthreads();
    float* sOf = reinterpret_cast<float*>(smem);        // [ROWS][129]
    #pragma unroll
    for (int t = 0; t < NTILE; t++){
      int col = (nb0 + t)*16 + l15;
      #pragma unroll
      for (int r = 0; r < 4; r++)
        sOf[(m0o + quad*4 + r)*129 + col] = oacc[t][r];
    }
    __syncthreads();
    const float* obl = obp + (size_t)layer*DM;
    for (int p = tid; p < ROWS*DM; p += NT){
      int r = p / DM, c = p - r*DM;
      sOf[r*129 + c] += xres[((size_t)bb_*ROWS + r)*DM + c] + obl[c];
    }
    __syncthreads();
    if (tid < 2*ROWS){
      int row = tid >> 1, half = tid & 1;
      float s = 0.f;
      for (int c = half*63; c < half*63 + 63; c++) s += sOf[row*129 + c];
      prs[tid] = s;
    }
    __syncthreads();
    if (tid < 2*ROWS && (tid & 1) == 0) smean[tid>>1] = (prs[tid] + prs[tid+1]) / (float)DM;
    __syncthreads();
    if (tid < 2*ROWS){
      int row = tid >> 1, half = tid & 1;
      float mn = smean[row];
      float s = 0.f;
      for (int c = half*63; c < half*63 + 63; c++){ float d = sOf[row*129 + c] - mn; s += d*d; }
      prs[tid] = s;
    }
    __syncthreads();
    if (tid < 2*ROWS && (tid & 1) == 0) srstd[tid>>1] = rsqrtf((prs[tid] + prs[tid+1])/(float)DM + 1e-5f);
    __syncthreads();
    const float* l1gl = l1g + (size_t)layer*DM;
    const float* l1bl = l1b + (size_t)layer*DM;
    for (int p = tid; p < ROWS*DM; p += NT){
      int r = p / DM, c = p - r*DM;
      xm[r*130 + c] = (sOf[r*129 + c] - smean[r])*srstd[r]*l1gl[c] + l1bl[c];
    }
    __syncthreads();
  }

  s8v aX[MT2][4];
  #pragma unroll
  for (int mt = 0; mt < MT2; mt++){
    #pragma unroll
    for (int ks = 0; ks < 4; ks++){
      #pragma unroll
      for (int jj2 = 0; jj2 < 8; jj2++){
        int c = ks*32 + quad*8 + jj2;
        float v = (c < DM) ? xm[(rowb + mt*16 + l15)*130 + c] : 0.f;
        aX[mt][ks][jj2] = (short)f2bf(v);
      }
    }
  }
  stage_w1_p(w1t, 0, wA0, tid);
  stage_w2_p(w2t, 0, wB0, tid);

  const float* b1l = b1 + (size_t)layer*DFF;
  f4v acc2[MT2][2];
  #pragma unroll
  for (int mt = 0; mt < MT2; mt++){ acc2[mt][0] = z4; acc2[mt][1] = z4; }

  for (int j = 0; j < 32; j++){
    u16* wAcur = (j & 1) ? wA1 : wA0;
    u16* wAnxt = (j & 1) ? wA0 : wA1;
    u16* wBcur = (j & 1) ? wB1 : wB0;
    u16* wBnxt = (j & 1) ? wB0 : wB1;
    __syncthreads();
    if (j < 31){
      stage_w1_p(w1t, j+1, wAnxt, tid);
      stage_w2_p(w2t, j+1, wBnxt, tid);
    }
    // GEMM1: MR rows x 16 ff; 4 B-reads, 4*MT2 MFMA
    f4v acc1[MT2];
    #pragma unroll
    for (int mt = 0; mt < MT2; mt++) acc1[mt] = z4;
    {
      int nloc = ng*16 + l15;
      #pragma unroll
      for (int ks = 0; ks < 4; ks++){
        int cg = (ks*4 + quad) ^ (nloc & 7);
        s8v b = *reinterpret_cast<const s8v*>(wAcur + nloc*128 + cg*8);
        #pragma unroll
        for (int mt = 0; mt < MT2; mt++)
          acc1[mt] = __builtin_amdgcn_mfma_f32_16x16x32_bf16(aX[mt][ks], b, acc1[mt], 0, 0, 0);
      }
    }
    // bias + GELU + pack, write to mg-shared Y tile (swizzled)
    {
      int col = ng*16 + l15;
      float bv = b1l[j*64 + col];
      #pragma unroll
      for (int mt = 0; mt < MT2; mt++){
        float y0 = gelu_fast(acc1[mt][0] + bv);
        float y1 = gelu_fast(acc1[mt][1] + bv);
        float y2 = gelu_fast(acc1[mt][2] + bv);
        float y3 = gelu_fast(acc1[mt][3] + bv);
        unsigned p01 = cvt_pk_bf16(y0, y1);
        unsigned p23 = cvt_pk_bf16(y2, y3);
        int r0 = mt*16 + quad*4;
        sYg[yaddr(r0,     col)] = (u16)p01;
        sYg[yaddr(r0 + 1, col)] = (u16)(p01 >> 16);
        sYg[yaddr(r0 + 2, col)] = (u16)p23;
        sYg[yaddr(r0 + 3, col)] = (u16)(p23 >> 16);
      }
    }
    lgkm_barrier();
    // GEMM2: MR rows x 32 out-cols, K=64; MT2 A-reads x2 + 4 B-reads, 4*MT2 MFMA
    #pragma unroll
    for (int ks2 = 0; ks2 < 2; ks2++){
      int ga = ((ks2*4 + quad) ^ (l15 & 7)) << 3;
      s8v amt[MT2];
      #pragma unroll
      for (int mt = 0; mt < MT2; mt++)
        amt[mt] = *reinterpret_cast<const s8v*>(sYg + (mt*16 + l15)*64 + ga);
      #pragma unroll
      for (int t = 0; t < 2; t++){
        int nloc = ng*32 + t*16 + l15;
        int cg = (ks2*4 + quad) ^ (nloc & 7);
        s8v b = *reinterpret_cast<const s8v*>(wBcur + nloc*64 + cg*8);
        #pragma unroll
        for (int mt = 0; mt < MT2; mt++)
          acc2[mt][t] = __builtin_amdgcn_mfma_f32_16x16x32_bf16(amt[mt], b, acc2[mt][t], 0, 0, 0);
      }
    }
  }

  // ---- shared epilogue: acc2 -> sO, bias+residual(xm), ln2 stats ----
  __syncthreads();
  float* sO = reinterpret_cast<float*>(smem);
  #pragma unroll
  for (int mt = 0; mt < MT2; mt++)
    #pragma unroll
    for (int t = 0; t < 2; t++)
      #pragma unroll
      for (int r = 0; r < 4; r++)
        sO[(rowb + mt*16 + quad*4 + r)*129 + ng*32 + t*16 + l15] = acc2[mt][t][r];
  __syncthreads();
  const float* b2l = b2w + (size_t)layer*DM;
  for (int p = tid; p < ROWS*DM; p += NT){
    int r = p / DM, c = p - r*DM;
    sO[r*129 + c] += b2l[c] + xm[r*130 + c];
  }
  __syncthreads();
  if (tid < 2*ROWS){
    int row = tid >> 1, half = tid & 1;
    float s = 0.f;
    for (int c = half*63; c < half*63 + 63; c++) s += sO[row*129 + c];
    prs[tid] = s;
  }
  __syncthreads();
  if (tid < 2*ROWS && (tid & 1) == 0) smean[tid>>1] = (prs[tid] + prs[tid+1]) / (float)DM;
  __syncthreads();
  if (tid < 2*ROWS){
    int row = tid >> 1, half = tid & 1;
    float mn = smean[row];
    float s = 0.f;
    for (int c = half*63; c < half*63 + 63; c++){ float d = sO[row*129 + c] - mn; s += d*d; }
    prs[tid] = s;
  }
  __syncthreads();
  if (tid < 2*ROWS && (tid & 1) == 0) srstd[tid>>1] = rsqrtf((prs[tid] + prs[tid+1])/(float)DM + 1e-5f);
  __syncthreads();
  const float* gl = g  + (size_t)layer*DM;
  const float* bl = bb + (size_t)layer*DM;

  if constexpr (ROWS == 128){
    // ===== fused DISTILL: conv(378)+BN+ELU+maxpool -> out2 (X2) + sQ =====
    float rv[16];
    #pragma unroll
    for (int k = 0; k < 16; k++){
      int p = tid + k*1024;
      if (p < 128*DM){
        int r = p / DM, c = p - r*DM;
        rv[k] = (sO[r*129 + c] - smean[r])*srstd[r]*gl[c] + bl[c];
      } else rv[k] = 0.f;
    }
    __syncthreads();
    u16* sAd = smem;
    #pragma unroll
    for (int k = 0; k < 16; k++){
      int p = tid + k*1024;
      if (p < 128*DM){
        int r = p / DM, c = p - r*DM;
        u16 bv = f2bf(rv[k]);
        sAd[((r + 1) & 127)*392 + c] = bv;
        sAd[r*392 + 126 + c] = bv;
        sAd[((r + 127) & 127)*392 + 252 + c] = bv;
      }
    }
    if (tid < 768){ int row = tid / 6, c2 = tid - row*6; sAd[row*392 + 378 + c2] = 0; }
    __syncthreads();
    const int mrow  = (wave & 7) * 16;
    const int tbase = (wave >> 3) * 4;
    f4v dac[4];
    dac[0]=z4; dac[1]=z4; dac[2]=z4; dac[3]=z4;
    for (int ks = 0; ks < 12; ks++){
      s8v a = *reinterpret_cast<const s8v*>(sAd + (mrow + l15)*392 + ks*32 + quad*8);
      const u16* wbp = wdist + (size_t)l15*384 + ks*32 + quad*8;
      #pragma unroll
      for (int t = 0; t < 4; t++){
        s8v bfr = *reinterpret_cast<const s8v*>(wbp + (size_t)(tbase + t)*16*384);
        dac[t] = __builtin_amdgcn_mfma_f32_16x16x32_bf16(a, bfr, dac[t], 0, 0, 0);
      }
    }
    __syncthreads();
    float* zsh = reinterpret_cast<float*>(smem);
    const float bnscale = 1.f / sqrtf(1.f + 1e-5f);
    #pragma unroll
    for (int t = 0; t < 4; t++){
      int co = (tbase + t)*16 + l15;
      if (co < DM){
        float cb = e1[co];
        float gg = e2[co] * bnscale, bv = e3[co];
        #pragma unroll
        for (int r = 0; r < 4; r++){
          int row = mrow + quad*4 + r;
          float z = (dac[t][r] + cb)*gg + bv;
          z = (z > 0.f) ? z : (__expf(z) - 1.f);
          zsh[row*130 + co] = z;
        }
      }
    }
    __syncthreads();
    // maxpool -> out2 (X2) AND sQ bf16 tile (reuses dead xm region)
    u16* sQ = smem + XMOFF;
    for (int p = tid; p < 64*128; p += 1024){
      int jj = p >> 7, co = p & 127;
      float best = 0.f;
      if (co < DM){
        best = zsh[(2*jj)*130 + co];
        if (jj > 0) best = fmaxf(best, zsh[(2*jj - 1)*130 + co]);
        best = fmaxf(best, zsh[(2*jj + 1)*130 + co]);
        out2[((size_t)bb_*64 + jj)*DM + co] = best;
      }
      sQ[jj*136 + co] = f2bf(best);
    }
    __syncthreads();
    // ===== fused QKV (L=64): M=64, N=384, K=128 from sQ =====
    {
      const int mq  = wave & 3;        // 4 m-tiles (64 rows)
      const int ngq = wave >> 2;       // 4 groups x 6 n-tiles
      f4v qa[6];
      #pragma unroll
      for (int t = 0; t < 6; t++) qa[t] = z4;
      #pragma unroll
      for (int ks = 0; ks < 4; ks++){
        s8v a = *reinterpret_cast<const s8v*>(sQ + (mq*16 + l15)*136 + ks*32 + quad*8);
        const u16* wbq = wqkv1 + (size_t)l15*128 + ks*32 + quad*8;
        #pragma unroll
        for (int t = 0; t < 6; t++){
          int nt = ngq*6 + t;
          s8v b = *reinterpret_cast<const s8v*>(wbq + (size_t)nt*16*128);
          qa[t] = __builtin_amdgcn_mfma_f32_16x16x32_bf16(a, b, qa[t], 0, 0, 0);
        }
      }
      #pragma unroll
      for (int t = 0; t < 6; t++){
        int col = (ngq*6 + t)*16 + l15;
        float bv = qb1[col];
        #pragma unroll
        for (int r = 0; r < 4; r++){
          int row = mq*16 + quad*4 + r;
          if (col < 256){
            qkvout[((size_t)bb_*64 + row)*256 + col] = qa[t][r] + bv;
          } else {
            int c = col - 256;
            if (c < DM){
              int h = c / DHd, d = c - h*DHd;
              vtout[((size_t)(bb_*NH + h)*DHd + d)*64 + row] = f2bf(qa[t][r] + bv);
            }
          }
        }
      }
    }
  } else {
    // ===== fused FINAL: ln2 in-place, enc-LN + fc -> d_out =====
    for (int p = tid; p < ROWS*DM; p += NT){
      int r = p / DM, c = p - r*DM;
      sO[r*129 + c] = (sO[r*129 + c] - smean[r])*srstd[r]*gl[c] + bl[c];
    }
    __syncthreads();
    if (tid < 2*ROWS){
      int row = tid >> 1, half = tid & 1;
      float s = 0.f;
      for (int c = half*63; c < half*63 + 63; c++) s += sO[row*129 + c];
      prs[tid] = s;
    }
    __syncthreads();
    if (tid < 2*ROWS && (tid & 1) == 0) smean[tid>>1] = (prs[tid] + prs[tid+1]) / (float)DM;
    __syncthreads();
    if (tid < 2*ROWS){
      int row = tid >> 1, half = tid & 1;
      float mn = smean[row];
      float s = 0.f;
      for (int c = half*63; c < half*63 + 63; c++){ float d = sO[row*129 + c] - mn; s += d*d; }
      prs[tid] = s;
    }
    __syncthreads();
    if (tid < 2*ROWS && (tid & 1) == 0) srstd[tid>>1] = rsqrtf((prs[tid] + prs[tid+1])/(float)DM + 1e-5f);
    __syncthreads();
    if (tid < DM){
      float gv = e1[tid], bv2 = e2[tid];   // enc_ln g/b
      float acc = e4[0];                   // fc_b
      for (int l = 0; l < 64; l++){
        float xn = (sO[l*129 + tid] - smean[l])*srstd[l]*gv + bv2;
        acc += xn * e3[l];                 // fc_w
      }
      out2[(size_t)bb_*DM + tid] = acc;
    }
  }
}

// ---------------- host launcher ----------------
extern "C" void kernel_launch(void* const* d_in, const int* in_sizes, int n_in,
                              void* d_out, int out_size, void* d_ws, size_t ws_size,
                              hipStream_t stream) {
  fp x_enc   = (fp)d_in[0];
  fp x_mark  = (fp)d_in[1];
  fp token_w = (fp)d_in[2];
  fp time_w  = (fp)d_in[3];
  fp time_b  = (fp)d_in[4];
  fp od_fc_w = (fp)d_in[5];
  fp od_bn_g = (fp)d_in[6];
  fp od_bn_b = (fp)d_in[7];
  fp od_ch_w = (fp)d_in[8];
  fp od_ch_b = (fp)d_in[9];
  fp od_fil_w= (fp)d_in[10];
  fp od_fil_b= (fp)d_in[11];
  fp od_sp_w = (fp)d_in[12];
  fp od_sp_b = (fp)d_in[13];
  fp od_ker_w= (fp)d_in[14];
  fp od_ker_b= (fp)d_in[15];
  fp od_wt   = (fp)d_in[16];
  fp q_w = (fp)d_in[17]; fp q_b = (fp)d_in[18];
  fp k_w = (fp)d_in[19]; fp k_b = (fp)d_in[20];
  fp v_w = (fp)d_in[21]; fp v_b = (fp)d_in[22];
  fp o_w = (fp)d_in[23]; fp o_b = (fp)d_in[24];
  fp f1w = (fp)d_in[25]; fp f1b = (fp)d_in[26];
  fp f2w = (fp)d_in[27]; fp f2b = (fp)d_in[28];
  fp ln1g= (fp)d_in[29]; fp ln1b= (fp)d_in[30];
  fp ln2g= (fp)d_in[31]; fp ln2b= (fp)d_in[32];
  fp cl_w= (fp)d_in[33]; fp cl_b= (fp)d_in[34];
  fp clbg= (fp)d_in[35]; fp clbb= (fp)d_in[36];
  fp elng= (fp)d_in[37]; fp elnb= (fp)d_in[38];
  fp fc_w= (fp)d_in[39]; fp fc_b= (fp)d_in[40];

  // ---- workspace layout (float units) ----
  const size_t OFF_IDX0 = 0;
  const size_t OFF_IDX1 = OFF_IDX0 + 3200;
  const size_t OFF_CH   = OFF_IDX1 + 1600;
  const size_t OFF_FIL  = OFF_CH  + (size_t)NB*DE;
  const size_t OFF_SP   = OFF_FIL + (size_t)NB*DE;
  const size_t OFF_KER  = OFF_SP  + (size_t)NB*4;
  const size_t OFF_VM   = OFF_KER + (size_t)NB*4;
  const size_t OFF_POS  = OFF_VM  + (size_t)NB*NH*DHd;
  const size_t OFF_UPD  = OFF_POS + (size_t)NB*NH*L0;
  const size_t OFF_STOP = OFF_UPD + (size_t)NB*NH*NTOP*DHd;
  const size_t OFF_WTS  = (OFF_STOP + (size_t)NB*NH*NTOP + 255) & ~(size_t)255;
  const size_t WTS_FLOATS = (2*262144 + 2*262144 + 2*49152 + 2*16384 + 49152 + 32768)/2 + 2*384;
  const size_t OFF_BIG  = (OFF_WTS + WTS_FLOATS + 255) & ~(size_t)255;
  const size_t SBUF     = (size_t)NB*DE*L0;
  const size_t TOTAL    = OFF_BIG + 4*SBUF;

  if (ws_size < TOTAL*sizeof(float)){
    hipLaunchKernelGGL(k_zero, dim3((out_size+255)/256), dim3(256), 0, stream,
                       (float*)d_out, out_size);
    return;
  }

  float* ws = (float*)d_ws;
  int* idx0 = (int*)(ws + OFF_IDX0);
  int* idx1 = (int*)(ws + OFF_IDX1);
  u16* vme  = (u16*)(ws + OFF_VM);
  int* posm  = (int*)(ws + OFF_POS);
  u16* updb  = (u16*)(ws + OFF_UPD);
  u16* w1tb  = (u16*)(ws + OFF_WTS);
  u16* w2tb  = w1tb + 2*262144;
  u16* wqkvb = w2tb + 2*262144;
  u16* wob   = wqkvb + 2*49152;
  u16* wdistb= wob + 2*16384;
  u16* wembb = wdistb + 49152;
  float* qkvbias = (float*)(wembb + 32768);

  // big buffers: X | QKV | X2 | VT(bf16, reinterpreted region)
  float* X    = ws + OFF_BIG;
  float* QKV  = X + SBUF;
  float* X2   = X + 2*SBUF;
  u16*   VTb  = (u16*)(X + 3*SBUF);

  hipLaunchKernelGGL(k_prep, dim3(1092), dim3(256), 0, stream,
                     idx0, idx1, token_w, cl_w, q_w, q_b, k_w, k_b, v_w, v_b, o_w,
                     wembb, wdistb, wqkvb, wob, qkvbias,
                     f1w, f2w, w1tb, w2tb);
  hipLaunchKernelGGL(k_front, dim3(NB), dim3(256), 0, stream,
                     x_enc, x_mark, wembb, time_w, time_b,
                     od_fc_w, od_bn_g, od_bn_b, od_ch_w, od_ch_b, od_fil_w, od_fil_b,
                     od_sp_w, od_sp_b, od_ker_w, od_ker_b, od_wt, X);

  // ----- layer 0 (L=128) -----
  hipLaunchKernelGGL(k_qkv_mfma, dim3(NB*L0/64), dim3(256), 0, stream,
                     X, wqkvb, qkvbias, QKV, VTb, 128, 7, 127);
  hipLaunchKernelGGL(k_attn, dim3(NB*NH), dim3(128), 0, stream,
                     QKV, VTb, idx0, L0, posm, vme, updb);
  // FFN L0: fused oproj(L0) head + loop + distil tail + QKV(L1) tail
  hipLaunchKernelGGL((k_ffn<128>), dim3(NB), dim3(1024), 0, stream,
                     w1tb, w2tb, f1b, f2b, ln2g, ln2b, 0,
                     wdistb, cl_b, clbg, clbb, cl_b,
                     X, vme, posm, updb, wob, o_b, ln1g, ln1b,
                     wqkvb + 49152, qkvbias + 384, QKV, VTb,
                     X2);

  // ----- layer 1 (L=64) -----
  hipLaunchKernelGGL(k_attn, dim3(NB*NH), dim3(128), 0, stream,
                     QKV, VTb, idx1, 64, posm, vme, updb);
  // FFN L1: fused oproj(L1) head + 16-wave loop + final tail -> d_out
  hipLaunchKernelGGL((k_ffn<64>), dim3(256), dim3(1024), 0, stream,
                     w1tb + 262144, w2tb + 262144, f1b, f2b, ln2g, ln2b, 1,
                     wdistb, elng, elnb, fc_w, fc_b,
                     X2, vme, posm, updb, wob, o_b, ln1g, ln1b,
                     wqkvb + 49152, qkvbias + 384, QKV, VTb,
                     (float*)d_out);
  (void)in_sizes; (void)n_in; (void)out_size; (void)ws_size;
}